// Round 3
// baseline (103832.825 us; speedup 1.0000x reference)
//
#include <hip/hip_runtime.h>
#include <hip/hip_cooperative_groups.h>
#include <cstddef>
#include <cstdint>

namespace cg = cooperative_groups;

#define T_INN 200
#define T_OUTT 400
#define BB 64
#define DENC 512
#define NMEL 80

typedef unsigned short u16;
typedef __bf16 bf16x8 __attribute__((ext_vector_type(8)));
typedef float f32x4 __attribute__((ext_vector_type(4)));

__device__ __forceinline__ float sigf(float x) { return 1.0f / (1.0f + expf(-x)); }

// round-to-nearest-even f32 -> bf16
__device__ __forceinline__ u16 f2bf(float f) {
  unsigned u = __float_as_uint(f);
  unsigned r = u + 0x7fffu + ((u >> 16) & 1u);
  return (u16)(r >> 16);
}

__device__ __forceinline__ bf16x8 ldbf8(const u16* p) { return *(const bf16x8*)p; }

// ---------------------------------------------------------------------------
// fp32 tiled GEMM for precompute: C[m][n] = act(sum_k A[m][k]*W[n][k])
// ---------------------------------------------------------------------------
__global__ __launch_bounds__(256) void gemm_pre_kernel(
    const float* __restrict__ A, int lda, const float* __restrict__ W, int ldw,
    float* __restrict__ C, u16* __restrict__ Cbf, int ldc, int K, int relu)
{
  __shared__ float As[16][66];
  __shared__ float Ws[16][66];
  const int tid = threadIdx.x;
  const int tn = tid & 15, tm = tid >> 4;
  const int n0 = blockIdx.x * 64;
  const int m0 = blockIdx.y * 64;
  float acc[4][4] = {{0.f}};
  for (int kt = 0; kt < K; kt += 16) {
#pragma unroll
    for (int i = 0; i < 4; i++) {
      int e = tid + 256 * i;
      int m = e >> 4, kk = e & 15;
      As[kk][m] = A[(size_t)(m0 + m) * lda + kt + kk];
    }
#pragma unroll
    for (int i = 0; i < 4; i++) {
      int e = tid + 256 * i;
      int n = e >> 4, kk = e & 15;
      Ws[kk][n] = W[(size_t)(n0 + n) * ldw + kt + kk];
    }
    __syncthreads();
#pragma unroll
    for (int kk = 0; kk < 16; kk++) {
      float2 a01 = *(const float2*)&As[kk][tm * 4];
      float2 a23 = *(const float2*)&As[kk][tm * 4 + 2];
      float2 w01 = *(const float2*)&Ws[kk][tn * 4];
      float2 w23 = *(const float2*)&Ws[kk][tn * 4 + 2];
      float a[4] = {a01.x, a01.y, a23.x, a23.y};
      float w[4] = {w01.x, w01.y, w23.x, w23.y};
#pragma unroll
      for (int mi = 0; mi < 4; mi++)
#pragma unroll
        for (int ni = 0; ni < 4; ni++)
          acc[mi][ni] = fmaf(a[mi], w[ni], acc[mi][ni]);
    }
    __syncthreads();
  }
#pragma unroll
  for (int mi = 0; mi < 4; mi++) {
    int m = m0 + tm * 4 + mi;
    float v0 = acc[mi][0], v1 = acc[mi][1], v2 = acc[mi][2], v3 = acc[mi][3];
    if (relu) {
      v0 = fmaxf(v0, 0.f); v1 = fmaxf(v1, 0.f);
      v2 = fmaxf(v2, 0.f); v3 = fmaxf(v3, 0.f);
    }
    if (Cbf) {
      u16* p = Cbf + (size_t)m * ldc + n0 + tn * 4;
      p[0] = f2bf(v0); p[1] = f2bf(v1); p[2] = f2bf(v2); p[3] = f2bf(v3);
    } else {
      float4 vv; vv.x = v0; vv.y = v1; vv.z = v2; vv.w = v3;
      *(float4*)&C[(size_t)m * ldc + n0 + tn * 4] = vv;
    }
  }
}

// ---------------------------------------------------------------------------
// Weight repack: W[n][k] fp32 -> bf16, MFMA B-fragment lane order.
// ---------------------------------------------------------------------------
__global__ __launch_bounds__(256) void pack_w_kernel(
    const float* __restrict__ W, u16* __restrict__ P,
    int K, int KTl, int ktOff, int KTtot, int total)
{
  int slot = blockIdx.x * 256 + threadIdx.x;
  if (slot >= total) return;
  int lane = slot & 63;
  int ktl = (slot >> 6) % KTl;
  int nt = slot / (64 * KTl);
  int n = nt * 16 + (lane & 15);
  int k = ktl * 32 + (lane >> 4) * 8;
  const float* src = W + (size_t)n * K + k;
  u16 tmp[8];
#pragma unroll
  for (int i = 0; i < 8; i++) tmp[i] = f2bf(src[i]);
  u16* dst = P + ((size_t)(nt * KTtot + (ktl + ktOff)) * 64 + lane) * 8;
  *(uint4*)dst = *(const uint4*)tmp;
}

// pm (b*t, a) -> pmT (b, a, t)
__global__ void transpose_pm_kernel(const float* __restrict__ pm, float* __restrict__ pmT)
{
  int b = blockIdx.z;
  int tT = blockIdx.x * 32, aT = blockIdx.y * 32;
  __shared__ float tile[32][33];
  int tx = threadIdx.x, ty = threadIdx.y;
#pragma unroll
  for (int i = 0; i < 4; i++) {
    int t = tT + ty + i * 8;
    int a = aT + tx;
    if (t < T_INN) tile[ty + i * 8][tx] = pm[((size_t)b * T_INN + t) * 128 + a];
  }
  __syncthreads();
#pragma unroll
  for (int i = 0; i < 4; i++) {
    int a = aT + ty + i * 8;
    int t = tT + tx;
    if (t < T_INN) pmT[((size_t)b * 128 + a) * T_INN + t] = tile[tx][ty + i * 8];
  }
}

// ---------------------------------------------------------------------------
// Persistent cooperative decode kernel, 256 blocks x 1024 threads.
// ---------------------------------------------------------------------------
struct SmemGates {
  float part[16][16][66];   // [kw][gate*4+reg][lane(+pad)] — conflict-free
  float gred[1024];
};
struct SmemAtt {
  float aS[T_INN], cS[T_INN], ahS[1024];
  float pp[128][9];
  float pqS[128];
  float convS[T_INN][33];
  float ep[4][256];
  float red[256];
  float awS[256];
  float cpart[1024];
};
union Smem { SmemGates g; SmemAtt a; };

struct DecParams {
  const u16* xs_bf;        // [400][64][256]
  const u16* Wa;           // packed, KT=56
  const u16* Wd;           // packed, KT=80
  const float* b_a;
  const float* b_d;
  float* ah; float* ac; float* dh; float* dc;
  u16* ah_bf;              // [2][64][1024] parity buffers
  u16* dh_bf;              // [2][64][1024]
  float* actx;             // [2][64][512] parity
  u16* actx_bf;            // [2][64][512] parity
  float* aw; float* awcum;
  const float* pmT;
  const float* Wq; const float* Wconv; const float* Wloc; const float* vvec;
  const int* lens; const float* enc;
  const float* Wp; const float* bp;
  float* outsOut; float* alignsOut;
};

// Full-block gates GEMM + LSTM activation. 16-wave split-K, LDS reduce.
// Load-hoisted lookahead-3 pipeline: ~15-25 loads in flight per wave.
template <int KT, int K0, int K1>
__device__ __forceinline__ void gates_lstm_block(
    const u16* __restrict__ A0, int lda0,
    const u16* __restrict__ A1, int lda1,
    const u16* __restrict__ A2, int lda2,
    const u16* __restrict__ Wpack, const float* __restrict__ bias,
    float* __restrict__ hOut, float* __restrict__ cSt, u16* __restrict__ hbfOut,
    int bq, int ms, int tid, SmemGates& sg)
{
  const int kw = tid >> 6, lane = tid & 63;
  const int mrow = lane & 15, ksub = (lane >> 4) * 8;
  constexpr int NI = (KT + 15) / 16;
  const size_t gstride = (size_t)KT * 32768;   // u16 elems between gate blocks

  bf16x8 aR[NI], b0R[NI], b1R[NI], b2R[NI], b3R[NI];

  auto issue = [&](int i) {
    int kt = kw + 16 * i;
    if (kt < KT) {
      int kb = kt * 32;
      const u16* Ap; int lda;
      if (kb < K0)            { Ap = A0; lda = lda0; }
      else if (kb < K0 + K1)  { Ap = A1; lda = lda1; kb -= K0; }
      else                    { Ap = A2; lda = lda2; kb -= (K0 + K1); }
      aR[i] = ldbf8(Ap + (size_t)(ms * 16 + mrow) * lda + kb + ksub);
      const u16* wb = Wpack + ((size_t)(bq * KT + kt) * 64 + lane) * 8;
      b0R[i] = ldbf8(wb);
      b1R[i] = ldbf8(wb + gstride);
      b2R[i] = ldbf8(wb + 2 * gstride);
      b3R[i] = ldbf8(wb + 3 * gstride);
    }
  };

#pragma unroll
  for (int i = 0; i < ((NI < 3) ? NI : 3); i++) issue(i);

  f32x4 acc0 = {0.f, 0.f, 0.f, 0.f};
  f32x4 acc1 = acc0, acc2 = acc0, acc3 = acc0;
#pragma unroll
  for (int i = 0; i < NI; i++) {
    if (i + 3 < NI) issue(i + 3);
    if (kw + 16 * i < KT) {
      acc0 = __builtin_amdgcn_mfma_f32_16x16x32_bf16(aR[i], b0R[i], acc0, 0, 0, 0);
      acc1 = __builtin_amdgcn_mfma_f32_16x16x32_bf16(aR[i], b1R[i], acc1, 0, 0, 0);
      acc2 = __builtin_amdgcn_mfma_f32_16x16x32_bf16(aR[i], b2R[i], acc2, 0, 0, 0);
      acc3 = __builtin_amdgcn_mfma_f32_16x16x32_bf16(aR[i], b3R[i], acc3, 0, 0, 0);
    }
  }

  // conflict-free partial store: part[kw][r][lane], bank = lane%32
#pragma unroll
  for (int r = 0; r < 4; r++) {
    sg.part[kw][r][lane]      = acc0[r];
    sg.part[kw][4 + r][lane]  = acc1[r];
    sg.part[kw][8 + r][lane]  = acc2[r];
    sg.part[kw][12 + r][lane] = acc3[r];
  }
  __syncthreads();
  {
    int g = tid >> 8, rc = tid & 255, row = rc >> 4, col = rc & 15;
    int ln = ((row >> 2) << 4) + col;
    int r = g * 4 + (row & 3);
    float s = 0.f;
#pragma unroll
    for (int k2 = 0; k2 < 16; k2++) s += sg.part[k2][r][ln];
    sg.gred[tid] = s;
  }
  __syncthreads();
  if (tid < 256) {
    int row = tid >> 4, col = tid & 15;
    int j = bq * 16 + col, m = ms * 16 + row;
    size_t idx = (size_t)m * 1024 + j;
    float gi = sg.gred[tid]       + bias[j];
    float gf = sg.gred[256 + tid] + bias[j + 1024];
    float gg = sg.gred[512 + tid] + bias[j + 2048];
    float go = sg.gred[768 + tid] + bias[j + 3072];
    float cn = sigf(gf) * cSt[idx] + sigf(gi) * tanhf(gg);
    cSt[idx] = cn;
    float hn = sigf(go) * tanhf(cn);
    hOut[idx] = hn;
    hbfOut[idx] = f2bf(hn);
  }
}

__global__ __launch_bounds__(1024, 4) void decode_kernel(DecParams p)
{
  cg::grid_group grid = cg::this_grid();
  const int b = blockIdx.x;
  const int bq = b & 63, ms = b >> 6;
  const int tid = threadIdx.x;
  const int g = tid >> 8, ti = tid & 255;

  __shared__ Smem sm;

  for (int t = 0; t <= T_OUTT; t++) {
    // ---------------- phase A: gatesD(t-1) then gatesA(t), all blocks -------
    if (t >= 1) {
      gates_lstm_block<80, 1024, 512>(
          p.ah_bf + (size_t)((t - 1) & 1) * 65536, 1024,
          p.actx_bf + (size_t)((t - 1) & 1) * 32768, 512,
          p.dh_bf + (size_t)(t & 1) * 65536, 1024,
          p.Wd, p.b_d, p.dh, p.dc,
          p.dh_bf + (size_t)((t - 1) & 1) * 65536,
          bq, ms, tid, sm.g);
      __syncthreads();
    }
    if (t < T_OUTT) {
      gates_lstm_block<56, 256, 512>(
          p.xs_bf + (size_t)t * 64 * 256, 256,
          p.actx_bf + (size_t)((t + 1) & 1) * 32768, 512,
          p.ah_bf + (size_t)((t + 1) & 1) * 65536, 1024,
          p.Wa, p.b_a, p.ah, p.ac,
          p.ah_bf + (size_t)(t & 1) * 65536,
          bq, ms, tid, sm.g);
    }
    grid.sync();

    // ---------------- phase B: attention(t) || outproj(t-1) || Wd prefetch --
    if (b < 64) {
      if (t < T_OUTT) {
        SmemAtt& sa = sm.a;
        float* actxW = p.actx + (size_t)(t & 1) * 32768;
        u16* actx_bfW = p.actx_bf + (size_t)(t & 1) * 32768;
        if (tid < T_INN) { sa.aS[tid] = p.aw[b * T_INN + tid]; sa.cS[tid] = p.awcum[b * T_INN + tid]; }
        sa.ahS[tid] = p.ah[(size_t)b * 1024 + tid];
        __syncthreads();
        {
          int a = tid >> 3, kc = tid & 7;
          const float4* wv = (const float4*)(p.Wq + (size_t)a * 1024 + kc * 128);
          const float4* hv = (const float4*)(sa.ahS + kc * 128);
          float s = 0.f;
#pragma unroll 8
          for (int i = 0; i < 32; i++) {
            int ii = (i + kc * 4) & 31;
            float4 wq = wv[ii], hh = hv[ii];
            s += wq.x * hh.x + wq.y * hh.y + wq.z * hh.z + wq.w * hh.w;
          }
          sa.pp[a][kc] = s;
        }
        __syncthreads();
        if (tid < 128) {
          float s = 0.f;
#pragma unroll
          for (int kc = 0; kc < 8; kc++) s += sa.pp[tid][kc];
          sa.pqS[tid] = s;
        }
        if (ti < T_INN) {
          // hoist aw/awcum window into registers, then 8 filters from regs
          float av[31], cvv[31];
#pragma unroll
          for (int k = 0; k < 31; k++) {
            int tt2 = ti + k - 15;
            bool ok = (tt2 >= 0 && tt2 < T_INN);
            av[k]  = ok ? sa.aS[tt2] : 0.f;
            cvv[k] = ok ? sa.cS[tt2] : 0.f;
          }
#pragma unroll
          for (int f8 = 0; f8 < 8; f8++) {
            int f = g * 8 + f8;
            float s = 0.f;
#pragma unroll
            for (int k = 0; k < 31; k++)
              s += p.Wconv[f * 62 + k] * av[k] + p.Wconv[f * 62 + 31 + k] * cvv[k];
            sa.convS[ti][f] = s;
          }
        }
        __syncthreads();
        float e = 0.f;
        if (ti < T_INN) {
          float cv[32];
#pragma unroll
          for (int f = 0; f < 32; f++) cv[f] = sa.convS[ti][f];
          const float* pm = p.pmT + ((size_t)b * 128 + g * 32) * T_INN + ti;
#pragma unroll 8
          for (int aa = 0; aa < 32; aa++) {
            int a = g * 32 + aa;
            float x = sa.pqS[a] + pm[(size_t)aa * T_INN];
            const float* wl2 = p.Wloc + a * 32;
#pragma unroll
            for (int f = 0; f < 32; f++) x += wl2[f] * cv[f];
            // fast tanh: 1 - 2/(e^2x + 1)
            float ex2 = __expf(2.f * x);
            e += p.vvec[a] * (1.f - 2.f * __builtin_amdgcn_rcpf(ex2 + 1.f));
          }
        }
        sa.ep[g][ti] = e;
        __syncthreads();
        float ev = -3.0e38f, ex = 0.f;
        if (tid < 256) {
          if (tid < T_INN) {
            ev = sa.ep[0][tid] + sa.ep[1][tid] + sa.ep[2][tid] + sa.ep[3][tid];
            if (tid >= p.lens[b]) ev = -100000000.0f;
          }
          sa.red[tid] = ev;
        }
        __syncthreads();
        for (int s2 = 128; s2 > 0; s2 >>= 1) {
          if (tid < s2) sa.red[tid] = fmaxf(sa.red[tid], sa.red[tid + s2]);
          __syncthreads();
        }
        float mx = sa.red[0];
        __syncthreads();
        if (tid < 256) { ex = (tid < T_INN) ? expf(ev - mx) : 0.f; sa.red[tid] = ex; }
        __syncthreads();
        for (int s2 = 128; s2 > 0; s2 >>= 1) {
          if (tid < s2) sa.red[tid] += sa.red[tid + s2];
          __syncthreads();
        }
        float inv = 1.0f / sa.red[0];
        if (tid < T_INN) {
          float a = ex * inv;
          sa.awS[tid] = a;
          p.aw[b * T_INN + tid] = a;
          p.awcum[b * T_INN + tid] = sa.cS[tid] + a;
          p.alignsOut[((size_t)b * T_OUTT + t) * T_INN + tid] = a;
        }
        __syncthreads();
        {
          int e0 = tid & 511, half = tid >> 9;
          const float* ep2 = p.enc + ((size_t)b * T_INN + half * 100) * DENC + e0;
          float s0 = 0.f, s1 = 0.f, s2 = 0.f, s3 = 0.f;
#pragma unroll 5
          for (int q = 0; q < 25; q++) {
            s0 += sa.awS[half * 100 + 4 * q + 0] * ep2[(size_t)(4 * q + 0) * DENC];
            s1 += sa.awS[half * 100 + 4 * q + 1] * ep2[(size_t)(4 * q + 1) * DENC];
            s2 += sa.awS[half * 100 + 4 * q + 2] * ep2[(size_t)(4 * q + 2) * DENC];
            s3 += sa.awS[half * 100 + 4 * q + 3] * ep2[(size_t)(4 * q + 3) * DENC];
          }
          sa.cpart[tid] = (s0 + s1) + (s2 + s3);
        }
        __syncthreads();
        if (tid < 512) {
          float v2 = sa.cpart[tid] + sa.cpart[512 + tid];
          actxW[b * DENC + tid] = v2;
          actx_bfW[b * DENC + tid] = f2bf(v2);
        }
      }
    } else if (b < 128) {
      if (t >= 1) {
        // outproj(t-1) for batch bo: reads dh (epoch t-1), actx[(t-1)&1]
        const int bo = b - 64;
        const float* actxR = p.actx + (size_t)((t - 1) & 1) * 32768;
        float s = 0.f;
        int m = tid / 12, sub = tid - m * 12;
        if (tid < 960) {
          const float4* w4 = (const float4*)(p.Wp + (size_t)m * 1536 + sub * 128);
          const float4* a4 = (sub < 8)
              ? (const float4*)(p.dh + (size_t)bo * 1024 + sub * 128)
              : (const float4*)(actxR + (size_t)bo * 512 + (sub - 8) * 128);
#pragma unroll 16
          for (int kk = 0; kk < 32; kk++) {
            float4 w = w4[kk], av = a4[kk];
            s += w.x * av.x + w.y * av.y + w.z * av.z + w.w * av.w;
          }
        }
        sm.g.gred[tid] = s;
        __syncthreads();
        if (tid < 80) {
          float acc2 = p.bp[tid];
#pragma unroll
          for (int i2 = 0; i2 < 12; i2++) acc2 += sm.g.gred[tid * 12 + i2];
          p.outsOut[((size_t)bo * T_OUTT + (t - 1)) * NMEL + tid] = acc2;
        }
      }
    } else {
      // blocks 128-255: prefetch Wd quad slice into this XCD's L2 for the
      // next step's gatesD (2 blocks per quad; same XCD as its consumers).
      if (t < T_OUTT) {
        const int q = b & 63;
        const int g0 = (b < 192) ? 0 : 2;
        unsigned acc = 0u;
#pragma unroll
        for (int g2 = 0; g2 < 2; g2++) {
          const uint4* c4 = (const uint4*)(p.Wd + (size_t)((g0 + g2) * 64 + q) * 80 * 512);
#pragma unroll
          for (int i = 0; i < 5; i++) {
            int idx = tid + i * 1024;
            uint4 v = c4[idx];
            acc ^= v.x ^ v.y ^ v.z ^ v.w;
          }
        }
        asm volatile("" :: "v"(acc));
      }
    }
    if (t == T_OUTT) break;
    grid.sync();
  }
}

extern "C" void kernel_launch(void* const* d_in, const int* in_sizes, int n_in,
                              void* d_out, int out_size, void* d_ws, size_t ws_size,
                              hipStream_t stream)
{
  const float* enc    = (const float*)d_in[0];
  const float* dec    = (const float*)d_in[1];
  const int*   lens   = (const int*)d_in[2];
  const float* W_p1   = (const float*)d_in[3];
  const float* W_p2   = (const float*)d_in[4];
  const float* W_ih_a = (const float*)d_in[5];
  const float* W_hh_a = (const float*)d_in[6];
  const float* b_a    = (const float*)d_in[7];
  const float* Wq     = (const float*)d_in[8];
  const float* Wmem   = (const float*)d_in[9];
  const float* vvec   = (const float*)d_in[10];
  const float* Wconv  = (const float*)d_in[11];
  const float* Wloc   = (const float*)d_in[12];
  const float* W_ih_d = (const float*)d_in[13];
  const float* W_hh_d = (const float*)d_in[14];
  const float* b_d    = (const float*)d_in[15];
  const float* Wp     = (const float*)d_in[16];
  const float* bp     = (const float*)d_in[17];

  float* ws = (float*)d_ws;
  size_t off = 0;
  u16* xs_bf = (u16*)(ws + off); off += (size_t)T_OUTT * 64 * 256 / 2;
  float* pmT = ws + off; off += (size_t)64 * 128 * T_INN;
  u16* Wa_pack = (u16*)(ws + off); off += (size_t)4096 * 1792 / 2;
  u16* Wd_pack = (u16*)(ws + off); off += (size_t)4096 * 2560 / 2;
  // state block (zero-initialized)
  float* stateBase = ws + off;
  float* ah    = stateBase;
  float* ac    = ah + 65536;
  float* dh    = ac + 65536;
  float* dc    = dh + 65536;
  float* actx  = dc + 65536;          // 2 x 64*512 (parity)
  float* aw    = actx + 2 * 32768;    // 64*200
  float* awcum = aw + 12800;
  u16* ah_bf   = (u16*)(awcum + 12800);          // 2 x 65536 u16
  u16* dh_bf   = ah_bf + 2 * 65536;              // 2 x 65536 u16
  u16* actx_bf = dh_bf + 2 * 65536;              // 2 x 32768 u16
  size_t stateFloats = 4 * 65536 + 2 * 32768 + 2 * 12800
                     + (2 * 65536 + 2 * 65536 + 2 * 32768) / 2;
  off += stateFloats;
  float* scratch = ws + off;          // precompute only
  float* h1 = scratch;                // 399*64 x 256
  float* pmt = scratch;               // reused after prenet

  float* outsOut   = (float*)d_out;
  float* alignsOut = outsOut + (size_t)BB * T_OUTT * NMEL;

  // zero recurrent state + t=0 prenet row (prenet(0)=0, no bias)
  hipMemsetAsync(stateBase, 0, stateFloats * sizeof(float), stream);
  hipMemsetAsync(xs_bf, 0, (size_t)64 * 256 * sizeof(u16), stream);

  // ---- precompute ----
  {
    int tot;
    tot = 256 * 24 * 64;
    pack_w_kernel<<<(tot + 255) / 256, 256, 0, stream>>>(W_ih_a, Wa_pack, 768, 24, 0, 56, tot);
    tot = 256 * 32 * 64;
    pack_w_kernel<<<(tot + 255) / 256, 256, 0, stream>>>(W_hh_a, Wa_pack, 1024, 32, 24, 56, tot);
    tot = 256 * 48 * 64;
    pack_w_kernel<<<(tot + 255) / 256, 256, 0, stream>>>(W_ih_d, Wd_pack, 1536, 48, 0, 80, tot);
    tot = 256 * 32 * 64;
    pack_w_kernel<<<(tot + 255) / 256, 256, 0, stream>>>(W_hh_d, Wd_pack, 1024, 32, 48, 80, tot);
  }
  gemm_pre_kernel<<<dim3(4, 399), 256, 0, stream>>>(dec, 80, W_p1, 80, h1, nullptr, 256, 80, 1);
  gemm_pre_kernel<<<dim3(4, 399), 256, 0, stream>>>(h1, 256, W_p2, 256, nullptr, xs_bf + 64 * 256, 256, 256, 1);
  gemm_pre_kernel<<<dim3(2, 200), 256, 0, stream>>>(enc, 512, Wmem, 512, pmt, nullptr, 128, 512, 0);
  transpose_pm_kernel<<<dim3(7, 4, 64), dim3(32, 8), 0, stream>>>(pmt, pmT);

  // ---- persistent cooperative decode loop ----
  DecParams dp;
  dp.xs_bf = xs_bf; dp.Wa = Wa_pack; dp.Wd = Wd_pack;
  dp.b_a = b_a; dp.b_d = b_d;
  dp.ah = ah; dp.ac = ac; dp.dh = dh; dp.dc = dc;
  dp.ah_bf = ah_bf; dp.dh_bf = dh_bf;
  dp.actx = actx; dp.actx_bf = actx_bf;
  dp.aw = aw; dp.awcum = awcum;
  dp.pmT = pmT; dp.Wq = Wq; dp.Wconv = Wconv; dp.Wloc = Wloc; dp.vvec = vvec;
  dp.lens = lens; dp.enc = enc; dp.Wp = Wp; dp.bp = bp;
  dp.outsOut = outsOut; dp.alignsOut = alignsOut;

  void* kargs[] = { (void*)&dp };
  hipLaunchCooperativeKernel(decode_kernel, dim3(256), dim3(1024), kargs, 0, stream);
}

// Round 4
// 97601.740 us; speedup vs baseline: 1.0638x; 1.0638x over previous
//
#include <hip/hip_runtime.h>
#include <hip/hip_cooperative_groups.h>
#include <cstddef>
#include <cstdint>

#define T_INN 200
#define T_OUTT 400
#define BB 64
#define DENC 512
#define NMEL 80

typedef unsigned short u16;
typedef unsigned long long u64;
typedef __bf16 bf16x8 __attribute__((ext_vector_type(8)));
typedef float f32x4 __attribute__((ext_vector_type(4)));

__device__ __forceinline__ float sigf(float x) { return 1.0f / (1.0f + expf(-x)); }

// round-to-nearest-even f32 -> bf16
__device__ __forceinline__ u16 f2bf(float f) {
  unsigned u = __float_as_uint(f);
  unsigned r = u + 0x7fffu + ((u >> 16) & 1u);
  return (u16)(r >> 16);
}

__device__ __forceinline__ bf16x8 ldbf8(const u16* p) { return *(const bf16x8*)p; }

// device-coherent (sc0 sc1) 16B load: bypasses (stale) L2, served from LLC.
// Compiler-tracked -> pipelines like a normal load.
__device__ __forceinline__ bf16x8 ldbf8_cc(const u16* p) {
  union { u64 q[2]; bf16x8 v; } u;
  u.q[0] = __hip_atomic_load((const u64*)p,     __ATOMIC_RELAXED, __HIP_MEMORY_SCOPE_AGENT);
  u.q[1] = __hip_atomic_load((const u64*)p + 1, __ATOMIC_RELAXED, __HIP_MEMORY_SCOPE_AGENT);
  return u.v;
}

// ---------------------------------------------------------------------------
// fp32 tiled GEMM for precompute: C[m][n] = act(sum_k A[m][k]*W[n][k])
// ---------------------------------------------------------------------------
__global__ __launch_bounds__(256) void gemm_pre_kernel(
    const float* __restrict__ A, int lda, const float* __restrict__ W, int ldw,
    float* __restrict__ C, u16* __restrict__ Cbf, int ldc, int K, int relu)
{
  __shared__ float As[16][66];
  __shared__ float Ws[16][66];
  const int tid = threadIdx.x;
  const int tn = tid & 15, tm = tid >> 4;
  const int n0 = blockIdx.x * 64;
  const int m0 = blockIdx.y * 64;
  float acc[4][4] = {{0.f}};
  for (int kt = 0; kt < K; kt += 16) {
#pragma unroll
    for (int i = 0; i < 4; i++) {
      int e = tid + 256 * i;
      int m = e >> 4, kk = e & 15;
      As[kk][m] = A[(size_t)(m0 + m) * lda + kt + kk];
    }
#pragma unroll
    for (int i = 0; i < 4; i++) {
      int e = tid + 256 * i;
      int n = e >> 4, kk = e & 15;
      Ws[kk][n] = W[(size_t)(n0 + n) * ldw + kt + kk];
    }
    __syncthreads();
#pragma unroll
    for (int kk = 0; kk < 16; kk++) {
      float2 a01 = *(const float2*)&As[kk][tm * 4];
      float2 a23 = *(const float2*)&As[kk][tm * 4 + 2];
      float2 w01 = *(const float2*)&Ws[kk][tn * 4];
      float2 w23 = *(const float2*)&Ws[kk][tn * 4 + 2];
      float a[4] = {a01.x, a01.y, a23.x, a23.y};
      float w[4] = {w01.x, w01.y, w23.x, w23.y};
#pragma unroll
      for (int mi = 0; mi < 4; mi++)
#pragma unroll
        for (int ni = 0; ni < 4; ni++)
          acc[mi][ni] = fmaf(a[mi], w[ni], acc[mi][ni]);
    }
    __syncthreads();
  }
#pragma unroll
  for (int mi = 0; mi < 4; mi++) {
    int m = m0 + tm * 4 + mi;
    float v0 = acc[mi][0], v1 = acc[mi][1], v2 = acc[mi][2], v3 = acc[mi][3];
    if (relu) {
      v0 = fmaxf(v0, 0.f); v1 = fmaxf(v1, 0.f);
      v2 = fmaxf(v2, 0.f); v3 = fmaxf(v3, 0.f);
    }
    if (Cbf) {
      u16* p = Cbf + (size_t)m * ldc + n0 + tn * 4;
      p[0] = f2bf(v0); p[1] = f2bf(v1); p[2] = f2bf(v2); p[3] = f2bf(v3);
    } else {
      float4 vv; vv.x = v0; vv.y = v1; vv.z = v2; vv.w = v3;
      *(float4*)&C[(size_t)m * ldc + n0 + tn * 4] = vv;
    }
  }
}

// ---------------------------------------------------------------------------
// Weight repack: W[n][k] fp32 -> bf16, MFMA B-fragment lane order.
// ---------------------------------------------------------------------------
__global__ __launch_bounds__(256) void pack_w_kernel(
    const float* __restrict__ W, u16* __restrict__ P,
    int K, int KTl, int ktOff, int KTtot, int total)
{
  int slot = blockIdx.x * 256 + threadIdx.x;
  if (slot >= total) return;
  int lane = slot & 63;
  int ktl = (slot >> 6) % KTl;
  int nt = slot / (64 * KTl);
  int n = nt * 16 + (lane & 15);
  int k = ktl * 32 + (lane >> 4) * 8;
  const float* src = W + (size_t)n * K + k;
  u16 tmp[8];
#pragma unroll
  for (int i = 0; i < 8; i++) tmp[i] = f2bf(src[i]);
  u16* dst = P + ((size_t)(nt * KTtot + (ktl + ktOff)) * 64 + lane) * 8;
  *(uint4*)dst = *(const uint4*)tmp;
}

// pm (b*t, a) -> pmT (b, a, t)
__global__ void transpose_pm_kernel(const float* __restrict__ pm, float* __restrict__ pmT)
{
  int b = blockIdx.z;
  int tT = blockIdx.x * 32, aT = blockIdx.y * 32;
  __shared__ float tile[32][33];
  int tx = threadIdx.x, ty = threadIdx.y;
#pragma unroll
  for (int i = 0; i < 4; i++) {
    int t = tT + ty + i * 8;
    int a = aT + tx;
    if (t < T_INN) tile[ty + i * 8][tx] = pm[((size_t)b * T_INN + t) * 128 + a];
  }
  __syncthreads();
#pragma unroll
  for (int i = 0; i < 4; i++) {
    int a = aT + ty + i * 8;
    int t = tT + tx;
    if (t < T_INN) pmT[((size_t)b * 128 + a) * T_INN + t] = tile[tx][ty + i * 8];
  }
}

// ---------------------------------------------------------------------------
// Persistent cooperative decode kernel, 256 blocks x 1024 threads.
// Cross-block state via sc0sc1 (agent-scope relaxed atomics) -> no L2
// invalidation at barriers -> weights stay L2-resident for all 400 steps.
// ---------------------------------------------------------------------------
struct SmemGates {
  float part[16][16][66];   // [kw][gate*4+reg][lane(+pad)] — conflict-free
  float gred[1024];
};
struct SmemAtt {
  float aS[T_INN], cS[T_INN], ahS[1024];
  float pp[128][9];
  float pqS[128];
  float convS[T_INN][33];
  float ep[4][256];
  float red[256];
  float awS[256];
  float cpart[1024];
};
union Smem { SmemGates g; SmemAtt a; };

struct DecParams {
  const u16* xs_bf;        // [400][64][256]
  const u16* Wa;           // packed, KT=64 (zero-padded from 56)
  const u16* Wd;           // packed, KT=80
  const float* b_a;
  const float* b_d;
  float* ah; float* ac; float* dh; float* dc;
  u16* ah_bf;              // [2][64][1024] parity buffers
  u16* dh_bf;              // [2][64][1024]
  float* actx;             // [2][64][512] parity
  u16* actx_bf;            // [2][64][512] parity
  float* aw; float* awcum;
  const float* pmT;
  const float* Wq; const float* Wconv; const float* Wloc; const float* vvec;
  const int* lens; const float* enc;
  const float* Wp; const float* bp;
  float* outsOut; float* alignsOut;
  unsigned* bar;
};

// grid barrier: monotonic counter; release arrive (writeback only, no L2
// invalidate on the spin) — weights stay cached.
__device__ __forceinline__ void gbar(unsigned* cnt, unsigned ep)
{
  __syncthreads();   // drains vmcnt -> all block stores complete at LLC
  if (threadIdx.x == 0) {
    __hip_atomic_fetch_add(cnt, 1u, __ATOMIC_RELEASE, __HIP_MEMORY_SCOPE_AGENT);
    while (__hip_atomic_load(cnt, __ATOMIC_RELAXED, __HIP_MEMORY_SCOPE_AGENT) < ep * 256u)
      __builtin_amdgcn_s_sleep(4);
  }
  __syncthreads();
  asm volatile("" ::: "memory");
}

// Full-block gates GEMM + LSTM activation. 16-wave split-K, LDS reduce.
// Depth-3 software pipeline over NAMED scalar fragments (no arrays, no
// runtime guards -> no scratch). KT must be a multiple of 16.
template <int KT, int K0, int K1>
__device__ __forceinline__ void gates_lstm_block(
    const u16* __restrict__ A0, int lda0,
    const u16* __restrict__ A1, int lda1,
    const u16* __restrict__ A2, int lda2,
    const u16* __restrict__ Wpack, const float* __restrict__ bias,
    float* __restrict__ hOut, float* __restrict__ cSt, u16* __restrict__ hbfOut,
    int bq, int ms, int tid, SmemGates& sg)
{
  const int kw = tid >> 6, lane = tid & 63;
  const int mrow = lane & 15, ksub = (lane >> 4) * 8;
  constexpr int NI = KT / 16;
  static_assert(NI >= 3 && NI <= 5, "pipeline written for NI in [3,5]");
  const size_t gstride = (size_t)KT * 32768;   // u16 elems between gate blocks
  const u16* wbase = Wpack + ((size_t)(bq * KT) * 64 + lane) * 8;
  const u16* pa0 = A0 + (size_t)(ms * 16 + mrow) * lda0 + ksub;
  const u16* pa1 = A1 + (size_t)(ms * 16 + mrow) * lda1 + ksub - K0;
  const u16* pa2 = A2 + (size_t)(ms * 16 + mrow) * lda2 + ksub - (K0 + K1);

  bf16x8 aA, w0A, w1A, w2A, w3A;
  bf16x8 aB, w0B, w1B, w2B, w3B;
  bf16x8 aC, w0C, w1C, w2C, w3C;

#define G_ISSUE(S, I)                                                         \
  {                                                                           \
    int kt = kw + 16 * (I);                                                   \
    int kb = kt * 32;                                                         \
    const u16* ap = (kb < K0) ? (pa0 + kb)                                    \
                  : ((kb < K0 + K1) ? (pa1 + kb) : (pa2 + kb));               \
    a##S = ldbf8_cc(ap);                                                      \
    const u16* wb = wbase + (size_t)kt * 512;                                 \
    w0##S = ldbf8(wb);                                                        \
    w1##S = ldbf8(wb + gstride);                                              \
    w2##S = ldbf8(wb + 2 * gstride);                                          \
    w3##S = ldbf8(wb + 3 * gstride);                                          \
  }
#define G_MFMA(S)                                                             \
  acc0 = __builtin_amdgcn_mfma_f32_16x16x32_bf16(a##S, w0##S, acc0, 0, 0, 0); \
  acc1 = __builtin_amdgcn_mfma_f32_16x16x32_bf16(a##S, w1##S, acc1, 0, 0, 0); \
  acc2 = __builtin_amdgcn_mfma_f32_16x16x32_bf16(a##S, w2##S, acc2, 0, 0, 0); \
  acc3 = __builtin_amdgcn_mfma_f32_16x16x32_bf16(a##S, w3##S, acc3, 0, 0, 0);

  f32x4 acc0 = {0.f, 0.f, 0.f, 0.f};
  f32x4 acc1 = acc0, acc2 = acc0, acc3 = acc0;

  G_ISSUE(A, 0)
  G_ISSUE(B, 1)
  G_ISSUE(C, 2)
  G_MFMA(A)
  if constexpr (NI > 3) G_ISSUE(A, 3)
  G_MFMA(B)
  if constexpr (NI > 4) G_ISSUE(B, 4)
  G_MFMA(C)
  if constexpr (NI > 3) { G_MFMA(A) }
  if constexpr (NI > 4) { G_MFMA(B) }

#undef G_ISSUE
#undef G_MFMA

  // conflict-free partial store: part[kw][r][lane], bank = lane%32
#pragma unroll
  for (int r = 0; r < 4; r++) {
    sg.part[kw][r][lane]      = acc0[r];
    sg.part[kw][4 + r][lane]  = acc1[r];
    sg.part[kw][8 + r][lane]  = acc2[r];
    sg.part[kw][12 + r][lane] = acc3[r];
  }
  __syncthreads();
  {
    int g = tid >> 8, rc = tid & 255, row = rc >> 4, col = rc & 15;
    int ln = ((row >> 2) << 4) + col;
    int r = g * 4 + (row & 3);
    float s = 0.f;
#pragma unroll
    for (int k2 = 0; k2 < 16; k2++) s += sg.part[k2][r][ln];
    sg.gred[tid] = s;
  }
  __syncthreads();
  if (tid < 256) {
    int row = tid >> 4, col = tid & 15;
    int j = bq * 16 + col, m = ms * 16 + row;
    size_t idx = (size_t)m * 1024 + j;
    float gi = sg.gred[tid]       + bias[j];
    float gf = sg.gred[256 + tid] + bias[j + 1024];
    float gg = sg.gred[512 + tid] + bias[j + 2048];
    float go = sg.gred[768 + tid] + bias[j + 3072];
    float cn = sigf(gf) * cSt[idx] + sigf(gi) * tanhf(gg);
    cSt[idx] = cn;                                   // block-private: cached
    float hn = sigf(go) * tanhf(cn);
    __hip_atomic_store(&hOut[idx], hn, __ATOMIC_RELAXED, __HIP_MEMORY_SCOPE_AGENT);
    __hip_atomic_store(&hbfOut[idx], (u16)f2bf(hn), __ATOMIC_RELAXED, __HIP_MEMORY_SCOPE_AGENT);
  }
}

__global__ __launch_bounds__(1024, 4) void decode_kernel(DecParams p)
{
  const int b = blockIdx.x;
  const int bq = b & 63, ms = b >> 6;
  const int tid = threadIdx.x;
  const int g = tid >> 8, ti = tid & 255;

  __shared__ Smem sm;
  unsigned ep = 0;

  for (int t = 0; t <= T_OUTT; t++) {
    // ---------------- phase A: gatesD(t-1) then gatesA(t), all blocks -------
    if (t >= 1) {
      gates_lstm_block<80, 1024, 512>(
          p.ah_bf + (size_t)((t - 1) & 1) * 65536, 1024,
          p.actx_bf + (size_t)((t - 1) & 1) * 32768, 512,
          p.dh_bf + (size_t)(t & 1) * 65536, 1024,
          p.Wd, p.b_d, p.dh, p.dc,
          p.dh_bf + (size_t)((t - 1) & 1) * 65536,
          bq, ms, tid, sm.g);
      __syncthreads();
    }
    if (t < T_OUTT) {
      gates_lstm_block<64, 256, 512>(
          p.xs_bf + (size_t)t * 64 * 256, 256,
          p.actx_bf + (size_t)((t + 1) & 1) * 32768, 512,
          p.ah_bf + (size_t)((t + 1) & 1) * 65536, 1024,
          p.Wa, p.b_a, p.ah, p.ac,
          p.ah_bf + (size_t)(t & 1) * 65536,
          bq, ms, tid, sm.g);
    }
    gbar(p.bar, ++ep);

    // ---------------- phase B: attention(t) || outproj(t-1) -----------------
    if (b < 64) {
      if (t < T_OUTT) {
        SmemAtt& sa = sm.a;
        float* actxW = p.actx + (size_t)(t & 1) * 32768;
        u16* actx_bfW = p.actx_bf + (size_t)(t & 1) * 32768;
        if (tid < T_INN) { sa.aS[tid] = p.aw[b * T_INN + tid]; sa.cS[tid] = p.awcum[b * T_INN + tid]; }
        sa.ahS[tid] = __hip_atomic_load(&p.ah[(size_t)b * 1024 + tid],
                                        __ATOMIC_RELAXED, __HIP_MEMORY_SCOPE_AGENT);
        __syncthreads();
        {
          int a = tid >> 3, kc = tid & 7;
          const float4* wv = (const float4*)(p.Wq + (size_t)a * 1024 + kc * 128);
          const float4* hv = (const float4*)(sa.ahS + kc * 128);
          float s = 0.f;
#pragma unroll 8
          for (int i = 0; i < 32; i++) {
            int ii = (i + kc * 4) & 31;
            float4 wq = wv[ii], hh = hv[ii];
            s += wq.x * hh.x + wq.y * hh.y + wq.z * hh.z + wq.w * hh.w;
          }
          sa.pp[a][kc] = s;
        }
        __syncthreads();
        if (tid < 128) {
          float s = 0.f;
#pragma unroll
          for (int kc = 0; kc < 8; kc++) s += sa.pp[tid][kc];
          sa.pqS[tid] = s;
        }
        if (ti < T_INN) {
          float av[31], cvv[31];
#pragma unroll
          for (int k = 0; k < 31; k++) {
            int tt2 = ti + k - 15;
            bool ok = (tt2 >= 0 && tt2 < T_INN);
            av[k]  = ok ? sa.aS[tt2] : 0.f;
            cvv[k] = ok ? sa.cS[tt2] : 0.f;
          }
#pragma unroll
          for (int f8 = 0; f8 < 8; f8++) {
            int f = g * 8 + f8;
            float s = 0.f;
#pragma unroll
            for (int k = 0; k < 31; k++)
              s += p.Wconv[f * 62 + k] * av[k] + p.Wconv[f * 62 + 31 + k] * cvv[k];
            sa.convS[ti][f] = s;
          }
        }
        __syncthreads();
        float e = 0.f;
        if (ti < T_INN) {
          float cv[32];
#pragma unroll
          for (int f = 0; f < 32; f++) cv[f] = sa.convS[ti][f];
          const float* pm = p.pmT + ((size_t)b * 128 + g * 32) * T_INN + ti;
#pragma unroll 8
          for (int aa = 0; aa < 32; aa++) {
            int a = g * 32 + aa;
            float x = sa.pqS[a] + pm[(size_t)aa * T_INN];
            const float* wl2 = p.Wloc + a * 32;
#pragma unroll
            for (int f = 0; f < 32; f++) x += wl2[f] * cv[f];
            float ex2 = __expf(2.f * x);
            e += p.vvec[a] * (1.f - 2.f * __builtin_amdgcn_rcpf(ex2 + 1.f));
          }
        }
        sa.ep[g][ti] = e;
        __syncthreads();
        float ev = -3.0e38f, ex = 0.f;
        if (tid < 256) {
          if (tid < T_INN) {
            ev = sa.ep[0][tid] + sa.ep[1][tid] + sa.ep[2][tid] + sa.ep[3][tid];
            if (tid >= p.lens[b]) ev = -100000000.0f;
          }
          sa.red[tid] = ev;
        }
        __syncthreads();
        for (int s2 = 128; s2 > 0; s2 >>= 1) {
          if (tid < s2) sa.red[tid] = fmaxf(sa.red[tid], sa.red[tid + s2]);
          __syncthreads();
        }
        float mx = sa.red[0];
        __syncthreads();
        if (tid < 256) { ex = (tid < T_INN) ? expf(ev - mx) : 0.f; sa.red[tid] = ex; }
        __syncthreads();
        for (int s2 = 128; s2 > 0; s2 >>= 1) {
          if (tid < s2) sa.red[tid] += sa.red[tid + s2];
          __syncthreads();
        }
        float inv = 1.0f / sa.red[0];
        if (tid < T_INN) {
          float a = ex * inv;
          sa.awS[tid] = a;
          p.aw[b * T_INN + tid] = a;                 // block-private: cached
          p.awcum[b * T_INN + tid] = sa.cS[tid] + a;
          p.alignsOut[((size_t)b * T_OUTT + t) * T_INN + tid] = a;
        }
        __syncthreads();
        {
          int e0 = tid & 511, half = tid >> 9;
          const float* ep2 = p.enc + ((size_t)b * T_INN + half * 100) * DENC + e0;
          float s0 = 0.f, s1 = 0.f, s2 = 0.f, s3 = 0.f;
#pragma unroll 5
          for (int q = 0; q < 25; q++) {
            s0 += sa.awS[half * 100 + 4 * q + 0] * ep2[(size_t)(4 * q + 0) * DENC];
            s1 += sa.awS[half * 100 + 4 * q + 1] * ep2[(size_t)(4 * q + 1) * DENC];
            s2 += sa.awS[half * 100 + 4 * q + 2] * ep2[(size_t)(4 * q + 2) * DENC];
            s3 += sa.awS[half * 100 + 4 * q + 3] * ep2[(size_t)(4 * q + 3) * DENC];
          }
          sa.cpart[tid] = (s0 + s1) + (s2 + s3);
        }
        __syncthreads();
        if (tid < 512) {
          float v2 = sa.cpart[tid] + sa.cpart[512 + tid];
          __hip_atomic_store(&actxW[b * DENC + tid], v2,
                             __ATOMIC_RELAXED, __HIP_MEMORY_SCOPE_AGENT);
          __hip_atomic_store(&actx_bfW[b * DENC + tid], (u16)f2bf(v2),
                             __ATOMIC_RELAXED, __HIP_MEMORY_SCOPE_AGENT);
        }
      }
    } else if (b < 128) {
      if (t >= 1) {
        const int bo = b - 64;
        const float* actxR = p.actx + (size_t)((t - 1) & 1) * 32768;
        float s = 0.f;
        int m = tid / 12, sub = tid - m * 12;
        if (tid < 960) {
          const float4* w4 = (const float4*)(p.Wp + (size_t)m * 1536 + sub * 128);
          const float* aBase = (sub < 8)
              ? (p.dh + (size_t)bo * 1024 + sub * 128)
              : (actxR + (size_t)bo * 512 + (sub - 8) * 128);
#pragma unroll 8
          for (int kk = 0; kk < 32; kk++) {
            float4 w = w4[kk];
            union { u64 q; float f[2]; } qa, qb;
            qa.q = __hip_atomic_load((const u64*)aBase + kk * 2,
                                     __ATOMIC_RELAXED, __HIP_MEMORY_SCOPE_AGENT);
            qb.q = __hip_atomic_load((const u64*)aBase + kk * 2 + 1,
                                     __ATOMIC_RELAXED, __HIP_MEMORY_SCOPE_AGENT);
            s += w.x * qa.f[0] + w.y * qa.f[1] + w.z * qb.f[0] + w.w * qb.f[1];
          }
        }
        sm.g.gred[tid] = s;
        __syncthreads();
        if (tid < 80) {
          float acc2 = p.bp[tid];
#pragma unroll
          for (int i2 = 0; i2 < 12; i2++) acc2 += sm.g.gred[tid * 12 + i2];
          p.outsOut[((size_t)bo * T_OUTT + (t - 1)) * NMEL + tid] = acc2;
        }
      }
    }
    if (t == T_OUTT) break;
    gbar(p.bar, ++ep);
  }
}

extern "C" void kernel_launch(void* const* d_in, const int* in_sizes, int n_in,
                              void* d_out, int out_size, void* d_ws, size_t ws_size,
                              hipStream_t stream)
{
  const float* enc    = (const float*)d_in[0];
  const float* dec    = (const float*)d_in[1];
  const int*   lens   = (const int*)d_in[2];
  const float* W_p1   = (const float*)d_in[3];
  const float* W_p2   = (const float*)d_in[4];
  const float* W_ih_a = (const float*)d_in[5];
  const float* W_hh_a = (const float*)d_in[6];
  const float* b_a    = (const float*)d_in[7];
  const float* Wq     = (const float*)d_in[8];
  const float* Wmem   = (const float*)d_in[9];
  const float* vvec   = (const float*)d_in[10];
  const float* Wconv  = (const float*)d_in[11];
  const float* Wloc   = (const float*)d_in[12];
  const float* W_ih_d = (const float*)d_in[13];
  const float* W_hh_d = (const float*)d_in[14];
  const float* b_d    = (const float*)d_in[15];
  const float* Wp     = (const float*)d_in[16];
  const float* bp     = (const float*)d_in[17];

  float* ws = (float*)d_ws;
  size_t off = 0;
  u16* xs_bf = (u16*)(ws + off); off += (size_t)T_OUTT * 64 * 256 / 2;
  float* pmT = ws + off; off += (size_t)64 * 128 * T_INN;
  u16* Wa_pack = (u16*)(ws + off); off += (size_t)4096 * 2048 / 2;   // KT=64 padded
  u16* Wd_pack = (u16*)(ws + off); off += (size_t)4096 * 2560 / 2;   // KT=80
  // state block (zero-initialized)
  float* stateBase = ws + off;
  float* ah    = stateBase;
  float* ac    = ah + 65536;
  float* dh    = ac + 65536;
  float* dc    = dh + 65536;
  float* actx  = dc + 65536;          // 2 x 64*512 (parity)
  float* aw    = actx + 2 * 32768;    // 64*200
  float* awcum = aw + 12800;
  u16* ah_bf   = (u16*)(awcum + 12800);          // 2 x 65536 u16
  u16* dh_bf   = ah_bf + 2 * 65536;              // 2 x 65536 u16
  u16* actx_bf = dh_bf + 2 * 65536;              // 2 x 32768 u16
  unsigned* barCnt = (unsigned*)(actx_bf + 2 * 32768);   // 64 B, zeroed
  size_t stateFloats = 4 * 65536 + 2 * 32768 + 2 * 12800
                     + (2 * 65536 + 2 * 65536 + 2 * 32768) / 2 + 16;
  off += stateFloats;
  float* scratch = ws + off;          // precompute only
  float* h1 = scratch;                // 399*64 x 256
  float* pmt = scratch;               // reused after prenet

  float* outsOut   = (float*)d_out;
  float* alignsOut = outsOut + (size_t)BB * T_OUTT * NMEL;

  // zero recurrent state + barrier + t=0 prenet row; zero Wa_pack (KT padding)
  hipMemsetAsync(stateBase, 0, stateFloats * sizeof(float), stream);
  hipMemsetAsync(xs_bf, 0, (size_t)64 * 256 * sizeof(u16), stream);
  hipMemsetAsync(Wa_pack, 0, (size_t)256 * 64 * 512 * sizeof(u16), stream);

  // ---- precompute ----
  {
    int tot;
    tot = 256 * 24 * 64;
    pack_w_kernel<<<(tot + 255) / 256, 256, 0, stream>>>(W_ih_a, Wa_pack, 768, 24, 0, 64, tot);
    tot = 256 * 32 * 64;
    pack_w_kernel<<<(tot + 255) / 256, 256, 0, stream>>>(W_hh_a, Wa_pack, 1024, 32, 24, 64, tot);
    tot = 256 * 48 * 64;
    pack_w_kernel<<<(tot + 255) / 256, 256, 0, stream>>>(W_ih_d, Wd_pack, 1536, 48, 0, 80, tot);
    tot = 256 * 32 * 64;
    pack_w_kernel<<<(tot + 255) / 256, 256, 0, stream>>>(W_hh_d, Wd_pack, 1024, 32, 48, 80, tot);
  }
  gemm_pre_kernel<<<dim3(4, 399), 256, 0, stream>>>(dec, 80, W_p1, 80, h1, nullptr, 256, 80, 1);
  gemm_pre_kernel<<<dim3(4, 399), 256, 0, stream>>>(h1, 256, W_p2, 256, nullptr, xs_bf + 64 * 256, 256, 256, 1);
  gemm_pre_kernel<<<dim3(2, 200), 256, 0, stream>>>(enc, 512, Wmem, 512, pmt, nullptr, 128, 512, 0);
  transpose_pm_kernel<<<dim3(7, 4, 64), dim3(32, 8), 0, stream>>>(pmt, pmT);

  // ---- persistent cooperative decode loop ----
  DecParams dp;
  dp.xs_bf = xs_bf; dp.Wa = Wa_pack; dp.Wd = Wd_pack;
  dp.b_a = b_a; dp.b_d = b_d;
  dp.ah = ah; dp.ac = ac; dp.dh = dh; dp.dc = dc;
  dp.ah_bf = ah_bf; dp.dh_bf = dh_bf;
  dp.actx = actx; dp.actx_bf = actx_bf;
  dp.aw = aw; dp.awcum = awcum;
  dp.pmT = pmT; dp.Wq = Wq; dp.Wconv = Wconv; dp.Wloc = Wloc; dp.vvec = vvec;
  dp.lens = lens; dp.enc = enc; dp.Wp = Wp; dp.bp = bp;
  dp.outsOut = outsOut; dp.alignsOut = alignsOut;
  dp.bar = barCnt;

  void* kargs[] = { (void*)&dp };
  hipLaunchCooperativeKernel(decode_kernel, dim3(256), dim3(1024), kargs, 0, stream);
}

// Round 5
// 55346.118 us; speedup vs baseline: 1.8761x; 1.7635x over previous
//
#include <hip/hip_runtime.h>
#include <cstddef>
#include <cstdint>

#define T_INN 200
#define T_OUTT 400
#define BB 64
#define DENC 512
#define NMEL 80

typedef unsigned short u16;
typedef __bf16 bf16x8 __attribute__((ext_vector_type(8)));
typedef float f32x4 __attribute__((ext_vector_type(4)));

__device__ __forceinline__ float sigf(float x) { return 1.0f / (1.0f + expf(-x)); }

// round-to-nearest-even f32 -> bf16
__device__ __forceinline__ u16 f2bf(float f) {
  unsigned u = __float_as_uint(f);
  unsigned r = u + 0x7fffu + ((u >> 16) & 1u);
  return (u16)(r >> 16);
}

__device__ __forceinline__ bf16x8 ldbf8(const u16* p) { return *(const bf16x8*)p; }

// ---------------------------------------------------------------------------
// fp32 tiled GEMM for precompute: C[m][n] = act(sum_k A[m][k]*W[n][k])
// grid.x = N/64, grid.y = M/64, block 256. Optional bf16 output.
// ---------------------------------------------------------------------------
__global__ __launch_bounds__(256) void gemm_pre_kernel(
    const float* __restrict__ A, int lda, const float* __restrict__ W, int ldw,
    float* __restrict__ C, u16* __restrict__ Cbf, int ldc, int K, int relu)
{
  __shared__ float As[16][66];
  __shared__ float Ws[16][66];
  const int tid = threadIdx.x;
  const int tn = tid & 15, tm = tid >> 4;
  const int n0 = blockIdx.x * 64;
  const int m0 = blockIdx.y * 64;
  float acc[4][4] = {{0.f}};
  for (int kt = 0; kt < K; kt += 16) {
#pragma unroll
    for (int i = 0; i < 4; i++) {
      int e = tid + 256 * i;
      int m = e >> 4, kk = e & 15;
      As[kk][m] = A[(size_t)(m0 + m) * lda + kt + kk];
    }
#pragma unroll
    for (int i = 0; i < 4; i++) {
      int e = tid + 256 * i;
      int n = e >> 4, kk = e & 15;
      Ws[kk][n] = W[(size_t)(n0 + n) * ldw + kt + kk];
    }
    __syncthreads();
#pragma unroll
    for (int kk = 0; kk < 16; kk++) {
      float2 a01 = *(const float2*)&As[kk][tm * 4];
      float2 a23 = *(const float2*)&As[kk][tm * 4 + 2];
      float2 w01 = *(const float2*)&Ws[kk][tn * 4];
      float2 w23 = *(const float2*)&Ws[kk][tn * 4 + 2];
      float a[4] = {a01.x, a01.y, a23.x, a23.y};
      float w[4] = {w01.x, w01.y, w23.x, w23.y};
#pragma unroll
      for (int mi = 0; mi < 4; mi++)
#pragma unroll
        for (int ni = 0; ni < 4; ni++)
          acc[mi][ni] = fmaf(a[mi], w[ni], acc[mi][ni]);
    }
    __syncthreads();
  }
#pragma unroll
  for (int mi = 0; mi < 4; mi++) {
    int m = m0 + tm * 4 + mi;
    float v0 = acc[mi][0], v1 = acc[mi][1], v2 = acc[mi][2], v3 = acc[mi][3];
    if (relu) {
      v0 = fmaxf(v0, 0.f); v1 = fmaxf(v1, 0.f);
      v2 = fmaxf(v2, 0.f); v3 = fmaxf(v3, 0.f);
    }
    if (Cbf) {
      u16* p = Cbf + (size_t)m * ldc + n0 + tn * 4;
      p[0] = f2bf(v0); p[1] = f2bf(v1); p[2] = f2bf(v2); p[3] = f2bf(v3);
    } else {
      float4 vv; vv.x = v0; vv.y = v1; vv.z = v2; vv.w = v3;
      *(float4*)&C[(size_t)m * ldc + n0 + tn * 4] = vv;
    }
  }
}

// ---------------------------------------------------------------------------
// Weight repack: W[n][k] fp32 -> bf16, MFMA B-fragment lane order.
// slot = (nt*KTtot + kt)*64 + lane ; element j: W[nt*16+(lane&15)][kt*32+(lane>>4)*8+j]
// ---------------------------------------------------------------------------
__global__ __launch_bounds__(256) void pack_w_kernel(
    const float* __restrict__ W, u16* __restrict__ P,
    int K, int KTl, int ktOff, int KTtot, int total)
{
  int slot = blockIdx.x * 256 + threadIdx.x;
  if (slot >= total) return;
  int lane = slot & 63;
  int ktl = (slot >> 6) % KTl;
  int nt = slot / (64 * KTl);
  int n = nt * 16 + (lane & 15);
  int k = ktl * 32 + (lane >> 4) * 8;
  const float* src = W + (size_t)n * K + k;
  u16 tmp[8];
#pragma unroll
  for (int i = 0; i < 8; i++) tmp[i] = f2bf(src[i]);
  u16* dst = P + ((size_t)(nt * KTtot + (ktl + ktOff)) * 64 + lane) * 8;
  *(uint4*)dst = *(const uint4*)tmp;
}

// pm (b*t, a) -> pmT (b, a, t)
__global__ void transpose_pm_kernel(const float* __restrict__ pm, float* __restrict__ pmT)
{
  int b = blockIdx.z;
  int tT = blockIdx.x * 32, aT = blockIdx.y * 32;
  __shared__ float tile[32][33];
  int tx = threadIdx.x, ty = threadIdx.y;
#pragma unroll
  for (int i = 0; i < 4; i++) {
    int t = tT + ty + i * 8;
    int a = aT + tx;
    if (t < T_INN) tile[ty + i * 8][tx] = pm[((size_t)b * T_INN + t) * 128 + a];
  }
  __syncthreads();
#pragma unroll
  for (int i = 0; i < 4; i++) {
    int a = aT + ty + i * 8;
    int t = tT + tx;
    if (t < T_INN) pmT[((size_t)b * 128 + a) * T_INN + t] = tile[tx][ty + i * 8];
  }
}

// ---------------------------------------------------------------------------
// Combined gates GEMM: grid (64, 16), block 256 (4 waves).
//   y in [0,8): gatesA(t)   split-K chunk y    (KT=56, nkt=7)   [skip t>=400]
//   y in [8,16): gatesD(t-1) split-K chunk y-8 (KT=80, nkt=10)  [skip t==0]
// Partials written to Cpart + y*64*4096. Body = proven baseline gates_mfma.
// ---------------------------------------------------------------------------
struct ASegs {
  const u16* A0; int lda0, k0;
  const u16* A1; int lda1, k1;
  const u16* A2; int lda2;
};

__global__ __launch_bounds__(256) void gates_both_kernel(
    ASegs sa, ASegs sd, const u16* __restrict__ Wa, const u16* __restrict__ Wd,
    float* __restrict__ Cpart, int t)
{
  const int y = blockIdx.y;
  ASegs s; const u16* Wpack; int KT, nkt;
  if (y < 8) {
    if (t >= T_OUTT) return;
    s = sa; Wpack = Wa; KT = 56; nkt = 7;
  } else {
    if (t < 1) return;
    s = sd; Wpack = Wd; KT = 80; nkt = 10;
  }
  const int kt0 = (y & 7) * nkt;
  const int tid = threadIdx.x;
  const int w = tid >> 6, lane = tid & 63;
  const int ntile = blockIdx.x * 4 + w;
  const int mrow = lane & 15;
  const int ksub = (lane >> 4) * 8;
  const int b01 = s.k0, b12 = s.k0 + s.k1;
  f32x4 acc0 = {0.f, 0.f, 0.f, 0.f};
  f32x4 acc1 = acc0, acc2 = acc0, acc3 = acc0;
  for (int kt = kt0; kt < kt0 + nkt; kt++) {
    int kb = kt * 32;
    const u16* Ap; int lda;
    if (kb < b01)      { Ap = s.A0; lda = s.lda0; }
    else if (kb < b12) { Ap = s.A1; lda = s.lda1; kb -= b01; }
    else               { Ap = s.A2; lda = s.lda2; kb -= b12; }
    const u16* abase = Ap + (size_t)mrow * lda + kb + ksub;
    bf16x8 bv = ldbf8(Wpack + ((size_t)(ntile * KT + kt) * 64 + lane) * 8);
    bf16x8 a0 = ldbf8(abase);
    bf16x8 a1 = ldbf8(abase + 16 * lda);
    bf16x8 a2 = ldbf8(abase + 32 * lda);
    bf16x8 a3 = ldbf8(abase + 48 * lda);
    acc0 = __builtin_amdgcn_mfma_f32_16x16x32_bf16(a0, bv, acc0, 0, 0, 0);
    acc1 = __builtin_amdgcn_mfma_f32_16x16x32_bf16(a1, bv, acc1, 0, 0, 0);
    acc2 = __builtin_amdgcn_mfma_f32_16x16x32_bf16(a2, bv, acc2, 0, 0, 0);
    acc3 = __builtin_amdgcn_mfma_f32_16x16x32_bf16(a3, bv, acc3, 0, 0, 0);
  }
  float* C = Cpart + (size_t)y * (64 * 4096);
  const int n = ntile * 16 + (lane & 15);
  const int rb = (lane >> 4) * 4;
#pragma unroll
  for (int r = 0; r < 4; r++) {
    C[(size_t)(0 + rb + r) * 4096 + n]  = acc0[r];
    C[(size_t)(16 + rb + r) * 4096 + n] = acc1[r];
    C[(size_t)(32 + rb + r) * 4096 + n] = acc2[r];
    C[(size_t)(48 + rb + r) * 4096 + n] = acc3[r];
  }
}

// ---------------------------------------------------------------------------
// Fused per-step kernel: 64 blocks (one per batch) x 1024 threads.
//   (a) reduce gd(t-1) partials -> dh LSTM activation  [t>=1]
//   (b) outproj(t-1) from LDS dh + actx(t-1)           [t>=1]
//   (c) reduce ga(t) partials -> ah LSTM activation    [t<400]
//   (d) attention(t) -> aw, awcum, actx, aligns        [t<400]
// All cross-phase state is block-private (batch b) or separated by kernel
// boundaries -> single-copy buffers, plain cached loads/stores.
// ---------------------------------------------------------------------------
__global__ __launch_bounds__(1024) void fused_step_kernel(
    const float* __restrict__ gpart,     // [16][64][4096]
    const float* __restrict__ b_a, const float* __restrict__ b_d,
    float* __restrict__ ac, float* __restrict__ dc,
    u16* __restrict__ ah_bf, u16* __restrict__ dh_bf,
    float* __restrict__ actx, u16* __restrict__ actx_bf,
    float* __restrict__ aw, float* __restrict__ awcum,
    const float* __restrict__ pmT, const float* __restrict__ Wq,
    const float* __restrict__ Wconv, const float* __restrict__ Wloc,
    const float* __restrict__ vvec, const int* __restrict__ lens,
    const float* __restrict__ enc, const float* __restrict__ Wp,
    const float* __restrict__ bp,
    float* __restrict__ outsOut, float* __restrict__ alignsOut, int t)
{
  const int b = blockIdx.x, tid = threadIdx.x;
  const int g = tid >> 8, ti = tid & 255;

  __shared__ float dhS[1024], ahS[1024];
  __shared__ float aS[T_INN], cS[T_INN];
  __shared__ float pp[128][9];
  __shared__ float pqS[128];
  __shared__ float convS[T_INN][33];
  __shared__ float ep[4][256];
  __shared__ float red[256];
  __shared__ float awS[256];
  __shared__ float cpart[1024];

  const size_t idx = (size_t)b * 1024 + tid;

  // (a) dh(t-1) = LSTM act of gd(t-1) partial sum
  if (t >= 1) {
    const float* g0 = gpart + (size_t)8 * (64 * 4096) + (size_t)b * 4096;
    float gi = b_d[tid], gf = b_d[tid + 1024], gg = b_d[tid + 2048], go = b_d[tid + 3072];
#pragma unroll
    for (int s = 0; s < 8; s++) {
      const float* gp = g0 + (size_t)s * (64 * 4096);
      gi += gp[tid]; gf += gp[tid + 1024]; gg += gp[tid + 2048]; go += gp[tid + 3072];
    }
    float cn = sigf(gf) * dc[idx] + sigf(gi) * tanhf(gg);
    dc[idx] = cn;
    float hn = sigf(go) * tanhf(cn);
    dh_bf[idx] = f2bf(hn);
    dhS[tid] = hn;
  }
  // (c-reduce) ah(t) = LSTM act of ga(t) partial sum
  if (t < T_OUTT) {
    const float* g0 = gpart + (size_t)b * 4096;
    float gi = b_a[tid], gf = b_a[tid + 1024], gg = b_a[tid + 2048], go = b_a[tid + 3072];
#pragma unroll
    for (int s = 0; s < 8; s++) {
      const float* gp = g0 + (size_t)s * (64 * 4096);
      gi += gp[tid]; gf += gp[tid + 1024]; gg += gp[tid + 2048]; go += gp[tid + 3072];
    }
    float cn = sigf(gf) * ac[idx] + sigf(gi) * tanhf(gg);
    ac[idx] = cn;
    float hn = sigf(go) * tanhf(cn);
    ah_bf[idx] = f2bf(hn);
    ahS[tid] = hn;
  }
  __syncthreads();

  // (b) outproj(t-1): out[b][m] = bp[m] + dh.Wp[:1024] + actx(t-1).Wp[1024:]
  if (t >= 1) {
    float s = 0.f;
    int m = tid / 12, sub = tid - m * 12;
    if (tid < 960) {
      const float4* w4 = (const float4*)(Wp + (size_t)m * 1536 + sub * 128);
      if (sub < 8) {
        const float* dv = dhS + sub * 128;
#pragma unroll 8
        for (int kk = 0; kk < 32; kk++) {
          float4 w = w4[kk];
          s += w.x * dv[4 * kk] + w.y * dv[4 * kk + 1]
             + w.z * dv[4 * kk + 2] + w.w * dv[4 * kk + 3];
        }
      } else {
        const float4* a4 = (const float4*)(actx + (size_t)b * 512 + (sub - 8) * 128);
#pragma unroll 8
        for (int kk = 0; kk < 32; kk++) {
          float4 w = w4[kk], av = a4[kk];
          s += w.x * av.x + w.y * av.y + w.z * av.z + w.w * av.w;
        }
      }
    }
    cpart[tid] = s;
    __syncthreads();
    if (tid < 80) {
      float acc2 = bp[tid];
#pragma unroll
      for (int i2 = 0; i2 < 12; i2++) acc2 += cpart[tid * 12 + i2];
      outsOut[((size_t)b * T_OUTT + (t - 1)) * NMEL + tid] = acc2;
    }
    __syncthreads();
  }
  if (t >= T_OUTT) return;

  // (d) attention — baseline att_kernel body, ah already in ahS.
  if (tid < T_INN) { aS[tid] = aw[b * T_INN + tid]; cS[tid] = awcum[b * T_INN + tid]; }
  __syncthreads();
  {
    int a = tid >> 3, kc = tid & 7;
    const float4* wv = (const float4*)(Wq + (size_t)a * 1024 + kc * 128);
    const float4* hv = (const float4*)(ahS + kc * 128);
    float s = 0.f;
#pragma unroll 8
    for (int i = 0; i < 32; i++) {
      float4 wq = wv[i], hh = hv[i];
      s += wq.x * hh.x + wq.y * hh.y + wq.z * hh.z + wq.w * hh.w;
    }
    pp[a][kc] = s;
  }
  __syncthreads();
  if (tid < 128) {
    float s = 0.f;
#pragma unroll
    for (int kc = 0; kc < 8; kc++) s += pp[tid][kc];
    pqS[tid] = s;
  }
  if (ti < T_INN) {
#pragma unroll
    for (int f8 = 0; f8 < 8; f8++) {
      int f = g * 8 + f8;
      float s = 0.f;
#pragma unroll
      for (int k = 0; k < 31; k++) {
        int tt = ti + k - 15;
        if (tt >= 0 && tt < T_INN)
          s += Wconv[f * 62 + k] * aS[tt] + Wconv[f * 62 + 31 + k] * cS[tt];
      }
      convS[ti][f] = s;
    }
  }
  __syncthreads();
  float e = 0.f;
  if (ti < T_INN) {
    const float* pm = pmT + ((size_t)b * 128 + g * 32) * T_INN + ti;
#pragma unroll 4
    for (int aa = 0; aa < 32; aa++) {
      int a = g * 32 + aa;
      float x = pqS[a] + pm[(size_t)aa * T_INN];
      const float* wl = Wloc + a * 32;
#pragma unroll
      for (int f = 0; f < 32; f++) x += wl[f] * convS[ti][f];
      e += vvec[a] * tanhf(x);
    }
  }
  ep[g][ti] = e;
  __syncthreads();
  float ev = -3.0e38f, ex = 0.f;
  if (tid < 256) {
    if (tid < T_INN) {
      ev = ep[0][tid] + ep[1][tid] + ep[2][tid] + ep[3][tid];
      if (tid >= lens[b]) ev = -100000000.0f;
    }
    red[tid] = ev;
  }
  __syncthreads();
  for (int s2 = 128; s2 > 0; s2 >>= 1) {
    if (tid < s2) red[tid] = fmaxf(red[tid], red[tid + s2]);
    __syncthreads();
  }
  float mx = red[0];
  __syncthreads();
  if (tid < 256) { ex = (tid < T_INN) ? expf(ev - mx) : 0.f; red[tid] = ex; }
  __syncthreads();
  for (int s2 = 128; s2 > 0; s2 >>= 1) {
    if (tid < s2) red[tid] += red[tid + s2];
    __syncthreads();
  }
  float inv = 1.0f / red[0];
  if (tid < T_INN) {
    float a = ex * inv;
    awS[tid] = a;
    aw[b * T_INN + tid] = a;
    awcum[b * T_INN + tid] = cS[tid] + a;
    alignsOut[((size_t)b * T_OUTT + t) * T_INN + tid] = a;
  }
  __syncthreads();
  {
    int e0 = tid & 511, half = tid >> 9;
    const float* ep2 = enc + ((size_t)b * T_INN + half * 100) * DENC + e0;
    float s = 0.f;
#pragma unroll 4
    for (int tt = 0; tt < 100; tt++) s += awS[half * 100 + tt] * ep2[(size_t)tt * DENC];
    cpart[tid] = s;
  }
  __syncthreads();
  if (tid < 512) {
    float v2 = cpart[tid] + cpart[512 + tid];
    actx[b * DENC + tid] = v2;
    actx_bf[b * DENC + tid] = f2bf(v2);
  }
}

extern "C" void kernel_launch(void* const* d_in, const int* in_sizes, int n_in,
                              void* d_out, int out_size, void* d_ws, size_t ws_size,
                              hipStream_t stream)
{
  const float* enc    = (const float*)d_in[0];
  const float* dec    = (const float*)d_in[1];
  const int*   lens   = (const int*)d_in[2];
  const float* W_p1   = (const float*)d_in[3];
  const float* W_p2   = (const float*)d_in[4];
  const float* W_ih_a = (const float*)d_in[5];
  const float* W_hh_a = (const float*)d_in[6];
  const float* b_a    = (const float*)d_in[7];
  const float* Wq     = (const float*)d_in[8];
  const float* Wmem   = (const float*)d_in[9];
  const float* vvec   = (const float*)d_in[10];
  const float* Wconv  = (const float*)d_in[11];
  const float* Wloc   = (const float*)d_in[12];
  const float* W_ih_d = (const float*)d_in[13];
  const float* W_hh_d = (const float*)d_in[14];
  const float* b_d    = (const float*)d_in[15];
  const float* Wp     = (const float*)d_in[16];
  const float* bp     = (const float*)d_in[17];

  float* ws = (float*)d_ws;
  size_t off = 0;
  u16* xs_bf = (u16*)(ws + off); off += (size_t)T_OUTT * 64 * 256 / 2;   // 3.28M fl
  float* pmT = ws + off; off += (size_t)64 * 128 * T_INN;                 // 1.64M fl
  u16* Wa_pack = (u16*)(ws + off); off += (size_t)4096 * 1792 / 2;        // 3.67M fl
  u16* Wd_pack = (u16*)(ws + off); off += (size_t)4096 * 2560 / 2;        // 5.24M fl
  // state block (zero-initialized): ac, dc, actx, aw, awcum, bf shadows
  float* stateBase = ws + off;
  float* ac    = stateBase;
  float* dc    = ac + 65536;
  float* actx  = dc + 65536;          // 64*512
  float* aw    = actx + 32768;        // 64*200
  float* awcum = aw + 12800;
  u16* ah_bf   = (u16*)(awcum + 12800);          // 65536 u16
  u16* dh_bf   = ah_bf + 65536;                  // 65536 u16
  u16* actx_bf = dh_bf + 65536;                  // 32768 u16
  size_t stateFloats = 2 * 65536 + 32768 + 2 * 12800 + (65536 + 65536 + 32768) / 2;
  off += stateFloats;
  float* scratch = ws + off;          // >= 6.54M floats: h1/pmt (precompute), 16 gate chunks (loop)
  float* h1 = scratch;                               // 399*64 x 256
  float* pmt = scratch;                              // reused after prenet

  float* outsOut   = (float*)d_out;
  float* alignsOut = outsOut + (size_t)BB * T_OUTT * NMEL;

  // zero recurrent state + t=0 prenet row (prenet(0)=0, no bias)
  hipMemsetAsync(stateBase, 0, stateFloats * sizeof(float), stream);
  hipMemsetAsync(xs_bf, 0, (size_t)64 * 256 * sizeof(u16), stream);

  // ---- precompute ----
  {
    int tot;
    tot = 256 * 24 * 64;
    pack_w_kernel<<<(tot + 255) / 256, 256, 0, stream>>>(W_ih_a, Wa_pack, 768, 24, 0, 56, tot);
    tot = 256 * 32 * 64;
    pack_w_kernel<<<(tot + 255) / 256, 256, 0, stream>>>(W_hh_a, Wa_pack, 1024, 32, 24, 56, tot);
    tot = 256 * 48 * 64;
    pack_w_kernel<<<(tot + 255) / 256, 256, 0, stream>>>(W_ih_d, Wd_pack, 1536, 48, 0, 80, tot);
    tot = 256 * 32 * 64;
    pack_w_kernel<<<(tot + 255) / 256, 256, 0, stream>>>(W_hh_d, Wd_pack, 1024, 32, 48, 80, tot);
  }
  gemm_pre_kernel<<<dim3(4, 399), 256, 0, stream>>>(dec, 80, W_p1, 80, h1, nullptr, 256, 80, 1);
  gemm_pre_kernel<<<dim3(4, 399), 256, 0, stream>>>(h1, 256, W_p2, 256, nullptr, xs_bf + 64 * 256, 256, 256, 1);
  gemm_pre_kernel<<<dim3(2, 200), 256, 0, stream>>>(enc, 512, Wmem, 512, pmt, nullptr, 128, 512, 0);
  transpose_pm_kernel<<<dim3(7, 4, 64), dim3(32, 8), 0, stream>>>(pmt, pmT);

  // ---- decode loop: 2 dispatches per step ----
  for (int t = 0; t <= T_OUTT; t++) {
    int tc = (t < T_OUTT) ? t : 0;   // dummy at t=400 (gatesA half skipped)
    ASegs sa;
    sa.A0 = xs_bf + (size_t)tc * 64 * 256; sa.lda0 = 256;  sa.k0 = 256;
    sa.A1 = actx_bf;                       sa.lda1 = 512;  sa.k1 = 512;
    sa.A2 = ah_bf;                         sa.lda2 = 1024;
    ASegs sd;
    sd.A0 = ah_bf;   sd.lda0 = 1024; sd.k0 = 1024;
    sd.A1 = actx_bf; sd.lda1 = 512;  sd.k1 = 512;
    sd.A2 = dh_bf;   sd.lda2 = 1024;
    gates_both_kernel<<<dim3(64, 16), 256, 0, stream>>>(sa, sd, Wa_pack, Wd_pack, scratch, t);
    fused_step_kernel<<<64, 1024, 0, stream>>>(scratch, b_a, b_d, ac, dc,
        ah_bf, dh_bf, actx, actx_bf, aw, awcum, pmT, Wq, Wconv, Wloc, vvec,
        lens, enc, Wp, bp, outsOut, alignsOut, t);
  }
}

// Round 6
// 37789.651 us; speedup vs baseline: 2.7477x; 1.4646x over previous
//
#include <hip/hip_runtime.h>
#include <cstddef>
#include <cstdint>

#define T_INN 200
#define T_OUTT 400
#define BB 64
#define DENC 512
#define NMEL 80

typedef unsigned short u16;
typedef __bf16 bf16x8 __attribute__((ext_vector_type(8)));
typedef float f32x4 __attribute__((ext_vector_type(4)));

__device__ __forceinline__ float sigf(float x) { return 1.0f / (1.0f + expf(-x)); }

// round-to-nearest-even f32 -> bf16
__device__ __forceinline__ u16 f2bf(float f) {
  unsigned u = __float_as_uint(f);
  unsigned r = u + 0x7fffu + ((u >> 16) & 1u);
  return (u16)(r >> 16);
}

__device__ __forceinline__ bf16x8 ldbf8(const u16* p) { return *(const bf16x8*)p; }

// ---------------------------------------------------------------------------
// fp32 tiled GEMM for precompute: C[m][n] = act(sum_k A[m][k]*W[n][k])
// ---------------------------------------------------------------------------
__global__ __launch_bounds__(256) void gemm_pre_kernel(
    const float* __restrict__ A, int lda, const float* __restrict__ W, int ldw,
    float* __restrict__ C, u16* __restrict__ Cbf, int ldc, int K, int relu)
{
  __shared__ float As[16][66];
  __shared__ float Ws[16][66];
  const int tid = threadIdx.x;
  const int tn = tid & 15, tm = tid >> 4;
  const int n0 = blockIdx.x * 64;
  const int m0 = blockIdx.y * 64;
  float acc[4][4] = {{0.f}};
  for (int kt = 0; kt < K; kt += 16) {
#pragma unroll
    for (int i = 0; i < 4; i++) {
      int e = tid + 256 * i;
      int m = e >> 4, kk = e & 15;
      As[kk][m] = A[(size_t)(m0 + m) * lda + kt + kk];
    }
#pragma unroll
    for (int i = 0; i < 4; i++) {
      int e = tid + 256 * i;
      int n = e >> 4, kk = e & 15;
      Ws[kk][n] = W[(size_t)(n0 + n) * ldw + kt + kk];
    }
    __syncthreads();
#pragma unroll
    for (int kk = 0; kk < 16; kk++) {
      float2 a01 = *(const float2*)&As[kk][tm * 4];
      float2 a23 = *(const float2*)&As[kk][tm * 4 + 2];
      float2 w01 = *(const float2*)&Ws[kk][tn * 4];
      float2 w23 = *(const float2*)&Ws[kk][tn * 4 + 2];
      float a[4] = {a01.x, a01.y, a23.x, a23.y};
      float w[4] = {w01.x, w01.y, w23.x, w23.y};
#pragma unroll
      for (int mi = 0; mi < 4; mi++)
#pragma unroll
        for (int ni = 0; ni < 4; ni++)
          acc[mi][ni] = fmaf(a[mi], w[ni], acc[mi][ni]);
    }
    __syncthreads();
  }
#pragma unroll
  for (int mi = 0; mi < 4; mi++) {
    int m = m0 + tm * 4 + mi;
    float v0 = acc[mi][0], v1 = acc[mi][1], v2 = acc[mi][2], v3 = acc[mi][3];
    if (relu) {
      v0 = fmaxf(v0, 0.f); v1 = fmaxf(v1, 0.f);
      v2 = fmaxf(v2, 0.f); v3 = fmaxf(v3, 0.f);
    }
    if (Cbf) {
      u16* p = Cbf + (size_t)m * ldc + n0 + tn * 4;
      p[0] = f2bf(v0); p[1] = f2bf(v1); p[2] = f2bf(v2); p[3] = f2bf(v3);
    } else {
      float4 vv; vv.x = v0; vv.y = v1; vv.z = v2; vv.w = v3;
      *(float4*)&C[(size_t)m * ldc + n0 + tn * 4] = vv;
    }
  }
}

// ---------------------------------------------------------------------------
// Weight repack: W[n][k] fp32 -> bf16, MFMA B-fragment lane order.
// ---------------------------------------------------------------------------
__global__ __launch_bounds__(256) void pack_w_kernel(
    const float* __restrict__ W, u16* __restrict__ P,
    int K, int KTl, int ktOff, int KTtot, int total)
{
  int slot = blockIdx.x * 256 + threadIdx.x;
  if (slot >= total) return;
  int lane = slot & 63;
  int ktl = (slot >> 6) % KTl;
  int nt = slot / (64 * KTl);
  int n = nt * 16 + (lane & 15);
  int k = ktl * 32 + (lane >> 4) * 8;
  const float* src = W + (size_t)n * K + k;
  u16 tmp[8];
#pragma unroll
  for (int i = 0; i < 8; i++) tmp[i] = f2bf(src[i]);
  u16* dst = P + ((size_t)(nt * KTtot + (ktl + ktOff)) * 64 + lane) * 8;
  *(uint4*)dst = *(const uint4*)tmp;
}

// pm (b*t, a) -> pmT (b, a, t)
__global__ void transpose_pm_kernel(const float* __restrict__ pm, float* __restrict__ pmT)
{
  int b = blockIdx.z;
  int tT = blockIdx.x * 32, aT = blockIdx.y * 32;
  __shared__ float tile[32][33];
  int tx = threadIdx.x, ty = threadIdx.y;
#pragma unroll
  for (int i = 0; i < 4; i++) {
    int t = tT + ty + i * 8;
    int a = aT + tx;
    if (t < T_INN) tile[ty + i * 8][tx] = pm[((size_t)b * T_INN + t) * 128 + a];
  }
  __syncthreads();
#pragma unroll
  for (int i = 0; i < 4; i++) {
    int a = aT + ty + i * 8;
    int t = tT + tx;
    if (t < T_INN) pmT[((size_t)b * 128 + a) * T_INN + t] = tile[tx][ty + i * 8];
  }
}

// ---------------------------------------------------------------------------
// Gates + LSTM activation, full-K per block. grid (64 quads, 4 mslices, 2
// gate-types), 1024 threads (16 waves, split-K over waves, LDS reduce).
// z=0: gatesA(t) KT=64 (zero-padded from 56); z=1: gatesD(t-1) KT=80.
// Fully-unrolled K loop, compile-time segment selection -> deep MLP.
// No partial round-trip: activation fused, writes h f32 + h bf16.
// ---------------------------------------------------------------------------
struct SmemGates {
  float part[16][16][66];   // [kw][gate*4+reg][lane(+pad)] conflict-free
  float gred[1024];
};

__global__ __launch_bounds__(1024) void gates_kernel(
    const u16* __restrict__ xs,        // [64][256] prenet rows for step t
    const u16* __restrict__ actx_bf,   // [64][512]
    const u16* __restrict__ ah_bf_r, u16* __restrict__ ah_bf_w,
    const u16* __restrict__ dh_bf_r, u16* __restrict__ dh_bf_w,
    const u16* __restrict__ Wa, const u16* __restrict__ Wd,
    const float* __restrict__ b_a, const float* __restrict__ b_d,
    float* __restrict__ ah, float* __restrict__ ac,
    float* __restrict__ dh, float* __restrict__ dc, int t)
{
  const int z = blockIdx.z;
  if (z == 0 && t >= T_OUTT) return;
  if (z == 1 && t < 1) return;
  const int bq = blockIdx.x, ms = blockIdx.y;
  const int tid = threadIdx.x;
  const int kw = tid >> 6, lane = tid & 63;
  const int mrow = lane & 15, ksub = (lane >> 4) * 8;
  const int row = ms * 16 + mrow;
  __shared__ SmemGates sg;

  f32x4 acc0 = {0.f, 0.f, 0.f, 0.f};
  f32x4 acc1 = acc0, acc2 = acc0, acc3 = acc0;
  const float* bias; float* hF; float* cSt; u16* hw;

  if (z == 0) {
    // gatesA(t): A = [xs(256) | actx(512) | ah(1024) | pad(256, W=0)]
    constexpr int KT = 64;
    const size_t gstride = (size_t)KT * 32768;
    const u16* wb0 = Wa + ((size_t)(bq * KT + kw * 4) * 64 + lane) * 8;
    // contiguous chunk kt = kw*4 + i ; segment is a pure (wave-uniform) fn of kw
    const u16* rb;
    if (kw < 2)      rb = xs      + (size_t)row * 256  + ksub + kw * 128;
    else if (kw < 6) rb = actx_bf + (size_t)row * 512  + ksub + kw * 128 - 256;
    else             rb = ah_bf_r + (size_t)row * 1024 + ksub + kw * 128 - 768;
#pragma unroll
    for (int i = 0; i < 4; i++) {
      bf16x8 a = ldbf8(rb + i * 32);
      const u16* wb = wb0 + (size_t)i * 512;
      bf16x8 w0 = ldbf8(wb);
      bf16x8 w1 = ldbf8(wb + gstride);
      bf16x8 w2 = ldbf8(wb + 2 * gstride);
      bf16x8 w3 = ldbf8(wb + 3 * gstride);
      acc0 = __builtin_amdgcn_mfma_f32_16x16x32_bf16(a, w0, acc0, 0, 0, 0);
      acc1 = __builtin_amdgcn_mfma_f32_16x16x32_bf16(a, w1, acc1, 0, 0, 0);
      acc2 = __builtin_amdgcn_mfma_f32_16x16x32_bf16(a, w2, acc2, 0, 0, 0);
      acc3 = __builtin_amdgcn_mfma_f32_16x16x32_bf16(a, w3, acc3, 0, 0, 0);
    }
    bias = b_a; hF = ah; cSt = ac; hw = ah_bf_w;
  } else {
    // gatesD(t-1): A = [ah(1024) | actx(512) | dh(1024)], KT=80
    constexpr int KT = 80;
    const size_t gstride = (size_t)KT * 32768;
    const u16* wb0 = Wd + ((size_t)(bq * KT + kw) * 64 + lane) * 8;
    // interleaved chunk kt = kw + 16*i ; segment is a compile-time fn of i
    const u16* a0b = ah_bf_r + (size_t)row * 1024 + ksub + kw * 32;
    const u16* a1b = actx_bf + (size_t)row * 512  + ksub + kw * 32;
    const u16* a2b = dh_bf_r + (size_t)row * 1024 + ksub + kw * 32;
#pragma unroll
    for (int i = 0; i < 5; i++) {
      const u16* ap = (i < 2) ? (a0b + i * 512) : ((i == 2) ? a1b : (a2b + (i - 3) * 512));
      bf16x8 a = ldbf8(ap);
      const u16* wb = wb0 + (size_t)i * (16 * 512);
      bf16x8 w0 = ldbf8(wb);
      bf16x8 w1 = ldbf8(wb + gstride);
      bf16x8 w2 = ldbf8(wb + 2 * gstride);
      bf16x8 w3 = ldbf8(wb + 3 * gstride);
      acc0 = __builtin_amdgcn_mfma_f32_16x16x32_bf16(a, w0, acc0, 0, 0, 0);
      acc1 = __builtin_amdgcn_mfma_f32_16x16x32_bf16(a, w1, acc1, 0, 0, 0);
      acc2 = __builtin_amdgcn_mfma_f32_16x16x32_bf16(a, w2, acc2, 0, 0, 0);
      acc3 = __builtin_amdgcn_mfma_f32_16x16x32_bf16(a, w3, acc3, 0, 0, 0);
    }
    bias = b_d; hF = dh; cSt = dc; hw = dh_bf_w;
  }

  // conflict-free partial store: part[kw][gate*4+r][lane]
#pragma unroll
  for (int r = 0; r < 4; r++) {
    sg.part[kw][r][lane]      = acc0[r];
    sg.part[kw][4 + r][lane]  = acc1[r];
    sg.part[kw][8 + r][lane]  = acc2[r];
    sg.part[kw][12 + r][lane] = acc3[r];
  }
  __syncthreads();
  {
    int g = tid >> 8, rc = tid & 255, rw = rc >> 4, col = rc & 15;
    int ln = ((rw >> 2) << 4) + col;
    int r = g * 4 + (rw & 3);
    float s = 0.f;
#pragma unroll
    for (int k2 = 0; k2 < 16; k2++) s += sg.part[k2][r][ln];
    sg.gred[tid] = s;
  }
  __syncthreads();
  if (tid < 256) {
    int rw = tid >> 4, col = tid & 15;
    int j = bq * 16 + col, m = ms * 16 + rw;
    size_t idx = (size_t)m * 1024 + j;
    float gi = sg.gred[tid]       + bias[j];
    float gf = sg.gred[256 + tid] + bias[j + 1024];
    float gg = sg.gred[512 + tid] + bias[j + 2048];
    float go = sg.gred[768 + tid] + bias[j + 3072];
    float cn = sigf(gf) * cSt[idx] + sigf(gi) * tanhf(gg);
    cSt[idx] = cn;
    float hn = sigf(go) * tanhf(cn);
    hF[idx] = hn;
    hw[idx] = f2bf(hn);
  }
}

// ---------------------------------------------------------------------------
// Fused step kernel: grid 128.
//   b in [0,64):   attention(t) for batch b        [skip t==400]
//   b in [64,128): outproj(t-1) for batch b-64     [skip t==0]
// actx f32 is parity-double-buffered (attention(t) writes slot t&1 while
// outproj reads slot (t-1)&1 concurrently).
// ---------------------------------------------------------------------------
__global__ __launch_bounds__(1024) void fused_step_kernel(
    const float* __restrict__ ah, const float* __restrict__ dh,
    float* __restrict__ actx /*[2][64][512]*/, u16* __restrict__ actx_bf,
    float* __restrict__ aw, float* __restrict__ awcum,
    const float* __restrict__ pmT, const float* __restrict__ Wq,
    const float* __restrict__ Wconv, const float* __restrict__ Wloc,
    const float* __restrict__ vvec, const int* __restrict__ lens,
    const float* __restrict__ enc, const float* __restrict__ Wp,
    const float* __restrict__ bp,
    float* __restrict__ outsOut, float* __restrict__ alignsOut, int t)
{
  const int tid = threadIdx.x;

  if (blockIdx.x >= 64) {
    // ---- outproj(t-1) ----
    if (t < 1) return;
    const int bo = blockIdx.x - 64;
    const float* actxR = actx + (size_t)((t - 1) & 1) * 32768;
    __shared__ float cp[1024];
    float s = 0.f;
    int m = tid / 12, sub = tid - m * 12;
    if (tid < 960) {
      const float4* w4 = (const float4*)(Wp + (size_t)m * 1536 + sub * 128);
      const float4* a4 = (sub < 8)
          ? (const float4*)(dh + (size_t)bo * 1024 + sub * 128)
          : (const float4*)(actxR + (size_t)bo * 512 + (sub - 8) * 128);
#pragma unroll 8
      for (int kk = 0; kk < 32; kk++) {
        float4 w = w4[kk], av = a4[kk];
        s += w.x * av.x + w.y * av.y + w.z * av.z + w.w * av.w;
      }
    }
    cp[tid] = s;
    __syncthreads();
    if (tid < 80) {
      float acc2 = bp[tid];
#pragma unroll
      for (int i2 = 0; i2 < 12; i2++) acc2 += cp[tid * 12 + i2];
      outsOut[((size_t)bo * T_OUTT + (t - 1)) * NMEL + tid] = acc2;
    }
    return;
  }

  // ---- attention(t) ----
  if (t >= T_OUTT) return;
  const int b = blockIdx.x;
  const int g = tid >> 8, ti = tid & 255;
  float* actxW = actx + (size_t)(t & 1) * 32768;

  __shared__ float aS[T_INN], cS[T_INN], ahS[1024];
  __shared__ float pp[128][9];
  __shared__ float pqS[128];
  __shared__ float convS[T_INN][33];
  __shared__ float ep[4][256];
  __shared__ float red[256];
  __shared__ float awS[256];
  __shared__ float cpart[1024];

  if (tid < T_INN) { aS[tid] = aw[b * T_INN + tid]; cS[tid] = awcum[b * T_INN + tid]; }
  ahS[tid] = ah[(size_t)b * 1024 + tid];
  __syncthreads();
  {
    int a = tid >> 3, kc = tid & 7;
    const float4* wv = (const float4*)(Wq + (size_t)a * 1024 + kc * 128);
    const float4* hv = (const float4*)(ahS + kc * 128);
    float s = 0.f;
#pragma unroll 8
    for (int i = 0; i < 32; i++) {
      float4 wq = wv[i], hh = hv[i];
      s += wq.x * hh.x + wq.y * hh.y + wq.z * hh.z + wq.w * hh.w;
    }
    pp[a][kc] = s;
  }
  __syncthreads();
  if (tid < 128) {
    float s = 0.f;
#pragma unroll
    for (int kc = 0; kc < 8; kc++) s += pp[tid][kc];
    pqS[tid] = s;
  }
  if (ti < T_INN) {
#pragma unroll
    for (int f8 = 0; f8 < 8; f8++) {
      int f = g * 8 + f8;
      float s = 0.f;
#pragma unroll
      for (int k = 0; k < 31; k++) {
        int tt = ti + k - 15;
        if (tt >= 0 && tt < T_INN)
          s += Wconv[f * 62 + k] * aS[tt] + Wconv[f * 62 + 31 + k] * cS[tt];
      }
      convS[ti][f] = s;
    }
  }
  __syncthreads();
  float e = 0.f;
  if (ti < T_INN) {
    const float* pm = pmT + ((size_t)b * 128 + g * 32) * T_INN + ti;
#pragma unroll 4
    for (int aa = 0; aa < 32; aa++) {
      int a = g * 32 + aa;
      float x = pqS[a] + pm[(size_t)aa * T_INN];
      const float* wl = Wloc + a * 32;
#pragma unroll
      for (int f = 0; f < 32; f++) x += wl[f] * convS[ti][f];
      // fast tanh: 1 - 2/(e^2x + 1)  (verified identical absmax in R3/R4)
      float ex2 = __expf(2.f * x);
      e += vvec[a] * (1.f - 2.f * __builtin_amdgcn_rcpf(ex2 + 1.f));
    }
  }
  ep[g][ti] = e;
  __syncthreads();
  float ev = -3.0e38f, ex = 0.f;
  if (tid < 256) {
    if (tid < T_INN) {
      ev = ep[0][tid] + ep[1][tid] + ep[2][tid] + ep[3][tid];
      if (tid >= lens[b]) ev = -100000000.0f;
    }
    red[tid] = ev;
  }
  __syncthreads();
  for (int s2 = 128; s2 > 0; s2 >>= 1) {
    if (tid < s2) red[tid] = fmaxf(red[tid], red[tid + s2]);
    __syncthreads();
  }
  float mx = red[0];
  __syncthreads();
  if (tid < 256) { ex = (tid < T_INN) ? expf(ev - mx) : 0.f; red[tid] = ex; }
  __syncthreads();
  for (int s2 = 128; s2 > 0; s2 >>= 1) {
    if (tid < s2) red[tid] += red[tid + s2];
    __syncthreads();
  }
  float inv = 1.0f / red[0];
  if (tid < T_INN) {
    float a = ex * inv;
    awS[tid] = a;
    aw[b * T_INN + tid] = a;
    awcum[b * T_INN + tid] = cS[tid] + a;
    alignsOut[((size_t)b * T_OUTT + t) * T_INN + tid] = a;
  }
  __syncthreads();
  {
    int e0 = tid & 511, half = tid >> 9;
    const float* ep2 = enc + ((size_t)b * T_INN + half * 100) * DENC + e0;
    float s = 0.f;
#pragma unroll 4
    for (int tt = 0; tt < 100; tt++) s += awS[half * 100 + tt] * ep2[(size_t)tt * DENC];
    cpart[tid] = s;
  }
  __syncthreads();
  if (tid < 512) {
    float v2 = cpart[tid] + cpart[512 + tid];
    actxW[b * DENC + tid] = v2;
    actx_bf[b * DENC + tid] = f2bf(v2);
  }
}

extern "C" void kernel_launch(void* const* d_in, const int* in_sizes, int n_in,
                              void* d_out, int out_size, void* d_ws, size_t ws_size,
                              hipStream_t stream)
{
  const float* enc    = (const float*)d_in[0];
  const float* dec    = (const float*)d_in[1];
  const int*   lens   = (const int*)d_in[2];
  const float* W_p1   = (const float*)d_in[3];
  const float* W_p2   = (const float*)d_in[4];
  const float* W_ih_a = (const float*)d_in[5];
  const float* W_hh_a = (const float*)d_in[6];
  const float* b_a    = (const float*)d_in[7];
  const float* Wq     = (const float*)d_in[8];
  const float* Wmem   = (const float*)d_in[9];
  const float* vvec   = (const float*)d_in[10];
  const float* Wconv  = (const float*)d_in[11];
  const float* Wloc   = (const float*)d_in[12];
  const float* W_ih_d = (const float*)d_in[13];
  const float* W_hh_d = (const float*)d_in[14];
  const float* b_d    = (const float*)d_in[15];
  const float* Wp     = (const float*)d_in[16];
  const float* bp     = (const float*)d_in[17];

  float* ws = (float*)d_ws;
  size_t off = 0;
  u16* xs_bf = (u16*)(ws + off); off += (size_t)T_OUTT * 64 * 256 / 2;
  float* pmT = ws + off; off += (size_t)64 * 128 * T_INN;
  u16* Wa_pack = (u16*)(ws + off); off += (size_t)4096 * 2048 / 2;   // KT=64 padded
  u16* Wd_pack = (u16*)(ws + off); off += (size_t)4096 * 2560 / 2;   // KT=80
  // state block (zero-initialized)
  float* stateBase = ws + off;
  float* ah    = stateBase;            // f32 [64][1024]
  float* dh    = ah + 65536;
  float* ac    = dh + 65536;
  float* dc    = ac + 65536;
  float* actx  = dc + 65536;           // [2][64][512] parity
  float* aw    = actx + 2 * 32768;
  float* awcum = aw + 12800;
  u16* ah_bf   = (u16*)(awcum + 12800);     // [2][64][1024]
  u16* dh_bf   = ah_bf + 2 * 65536;         // [2][64][1024]
  u16* actx_bf = dh_bf + 2 * 65536;         // [64][512]
  size_t stateFloats = 4 * 65536 + 2 * 32768 + 2 * 12800
                     + (2 * 65536 + 2 * 65536 + 32768) / 2;
  off += stateFloats;
  float* scratch = ws + off;           // precompute only
  float* h1 = scratch;                 // 399*64 x 256
  float* pmt = scratch;                // reused after prenet

  float* outsOut   = (float*)d_out;
  float* alignsOut = outsOut + (size_t)BB * T_OUTT * NMEL;

  // zero recurrent state + t=0 prenet row; zero Wa_pack (KT padding)
  hipMemsetAsync(stateBase, 0, stateFloats * sizeof(float), stream);
  hipMemsetAsync(xs_bf, 0, (size_t)64 * 256 * sizeof(u16), stream);
  hipMemsetAsync(Wa_pack, 0, (size_t)4096 * 2048 * sizeof(u16), stream);

  // ---- precompute ----
  {
    int tot;
    tot = 256 * 24 * 64;
    pack_w_kernel<<<(tot + 255) / 256, 256, 0, stream>>>(W_ih_a, Wa_pack, 768, 24, 0, 64, tot);
    tot = 256 * 32 * 64;
    pack_w_kernel<<<(tot + 255) / 256, 256, 0, stream>>>(W_hh_a, Wa_pack, 1024, 32, 24, 64, tot);
    tot = 256 * 48 * 64;
    pack_w_kernel<<<(tot + 255) / 256, 256, 0, stream>>>(W_ih_d, Wd_pack, 1536, 48, 0, 80, tot);
    tot = 256 * 32 * 64;
    pack_w_kernel<<<(tot + 255) / 256, 256, 0, stream>>>(W_hh_d, Wd_pack, 1024, 32, 48, 80, tot);
  }
  gemm_pre_kernel<<<dim3(4, 399), 256, 0, stream>>>(dec, 80, W_p1, 80, h1, nullptr, 256, 80, 1);
  gemm_pre_kernel<<<dim3(4, 399), 256, 0, stream>>>(h1, 256, W_p2, 256, nullptr, xs_bf + 64 * 256, 256, 256, 1);
  gemm_pre_kernel<<<dim3(2, 200), 256, 0, stream>>>(enc, 512, Wmem, 512, pmt, nullptr, 128, 512, 0);
  transpose_pm_kernel<<<dim3(7, 4, 64), dim3(32, 8), 0, stream>>>(pmt, pmT);

  // ---- decode loop: 2 dispatches per step ----
  // parity: at step t, gatesA writes ah_bf[t&1], reads ah_bf[(t+1)&1];
  //         gatesD (computes dh(t-1)) reads dh_bf[t&1], writes dh_bf[(t+1)&1].
  for (int t = 0; t <= T_OUTT; t++) {
    int tc = (t < T_OUTT) ? t : 0;
    gates_kernel<<<dim3(64, 4, 2), 1024, 0, stream>>>(
        xs_bf + (size_t)tc * 64 * 256,
        actx_bf,
        ah_bf + (size_t)((t + 1) & 1) * 65536, ah_bf + (size_t)(t & 1) * 65536,
        dh_bf + (size_t)(t & 1) * 65536,       dh_bf + (size_t)((t + 1) & 1) * 65536,
        Wa_pack, Wd_pack, b_a, b_d, ah, ac, dh, dc, t);
    fused_step_kernel<<<128, 1024, 0, stream>>>(
        ah, dh, actx, actx_bf, aw, awcum, pmT, Wq, Wconv, Wloc, vvec,
        lens, enc, Wp, bp, outsOut, alignsOut, t);
  }
}